// Round 1
// baseline (5528.912 us; speedup 1.0000x reference)
//
#include <hip/hip_runtime.h>

#define N_NODES 50000
#define DIM 128
#define BN_EPS 1e-5f

// ---------------- zero ----------------
__global__ __launch_bounds__(256) void zero4_kernel(float4* __restrict__ p, int n4) {
    int i = blockIdx.x * 256 + threadIdx.x;
    if (i < n4) p[i] = make_float4(0.f, 0.f, 0.f, 0.f);
}

// ---------------- scatter-add aggregation ----------------
// 32 threads per edge, one float4 each (128 features)
__global__ __launch_bounds__(256) void agg_kernel(const float* __restrict__ x,
                                                  const int* __restrict__ src,
                                                  const int* __restrict__ dst,
                                                  float* __restrict__ agg, int nE) {
    int gid = blockIdx.x * 256 + threadIdx.x;
    int e = gid >> 5;
    if (e >= nE) return;
    int f = gid & 31;
    int s = src[e], d = dst[e];
    float4 v = ((const float4*)x)[(size_t)s * 32 + f];
    float* a = agg + (size_t)d * DIM + f * 4;
    atomicAdd(a + 0, v.x);
    atomicAdd(a + 1, v.y);
    atomicAdd(a + 2, v.z);
    atomicAdd(a + 3, v.w);
}

// ---------------- C[M x 128] = relu(A (+A2) @ W + b) ----------------
// block 256, tile 64 rows x 128 cols, per-thread 8x4
template<bool RELU, bool ADD>
__global__ __launch_bounds__(256) void mm_kernel(const float* __restrict__ A,
                                                 const float* __restrict__ A2,
                                                 const float* __restrict__ W,
                                                 const float* __restrict__ b,
                                                 float* __restrict__ C, int M) {
    __shared__ float As[64][33];
    __shared__ float Ws[32][128];
    const int tid = threadIdx.x;
    const int tx = tid & 31;   // col group: cols tx*4..tx*4+3
    const int ty = tid >> 5;   // row group: rows ty*8..ty*8+7
    const int row0 = blockIdx.x * 64;
    float acc[8][4] = {};

    for (int kb = 0; kb < 128; kb += 32) {
        // stage A chunk: 64 rows x 32 cols
        {
            const int c4 = tid & 7;
            const int rr = tid >> 3;
            #pragma unroll
            for (int p = 0; p < 2; ++p) {
                int row = row0 + rr + p * 32;
                float4 v = make_float4(0.f, 0.f, 0.f, 0.f);
                if (row < M) {
                    v = ((const float4*)(A + (size_t)row * DIM + kb))[c4];
                    if (ADD) {
                        float4 u = ((const float4*)(A2 + (size_t)row * DIM + kb))[c4];
                        v.x += u.x; v.y += u.y; v.z += u.z; v.w += u.w;
                    }
                }
                As[rr + p * 32][c4 * 4 + 0] = v.x;
                As[rr + p * 32][c4 * 4 + 1] = v.y;
                As[rr + p * 32][c4 * 4 + 2] = v.z;
                As[rr + p * 32][c4 * 4 + 3] = v.w;
            }
        }
        // stage W chunk: 32 rows x 128 cols
        {
            const int wc4 = tid & 31;
            const int wr = tid >> 5;
            #pragma unroll
            for (int p = 0; p < 4; ++p) {
                float4 v = ((const float4*)(W + (size_t)(kb + wr + p * 8) * DIM))[wc4];
                *((float4*)&Ws[wr + p * 8][wc4 * 4]) = v;
            }
        }
        __syncthreads();
        #pragma unroll
        for (int kk = 0; kk < 32; ++kk) {
            const float4 wv = *((const float4*)&Ws[kk][tx * 4]);
            #pragma unroll
            for (int r = 0; r < 8; ++r) {
                float a = As[ty * 8 + r][kk];
                acc[r][0] += a * wv.x;
                acc[r][1] += a * wv.y;
                acc[r][2] += a * wv.z;
                acc[r][3] += a * wv.w;
            }
        }
        __syncthreads();
    }

    const float4 bv = *((const float4*)&b[tx * 4]);
    #pragma unroll
    for (int r = 0; r < 8; ++r) {
        int row = row0 + ty * 8 + r;
        if (row < M) {
            float4 o;
            o.x = acc[r][0] + bv.x;
            o.y = acc[r][1] + bv.y;
            o.z = acc[r][2] + bv.z;
            o.w = acc[r][3] + bv.w;
            if (RELU) {
                o.x = fmaxf(o.x, 0.f); o.y = fmaxf(o.y, 0.f);
                o.z = fmaxf(o.z, 0.f); o.w = fmaxf(o.w, 0.f);
            }
            ((float4*)(C + (size_t)row * DIM))[tx] = o;
        }
    }
}

// ---------------- C[M x 2] = relu(A @ W(128x2) + b) ----------------
__global__ __launch_bounds__(256) void mm2out_kernel(const float* __restrict__ A,
                                                     const float* __restrict__ W,
                                                     const float* __restrict__ b,
                                                     float* __restrict__ C, int M) {
    __shared__ float Ws[256];
    int tid = threadIdx.x;
    Ws[tid] = W[tid];
    __syncthreads();
    int row = blockIdx.x * 256 + tid;
    if (row >= M) return;
    const float4* a4 = (const float4*)(A + (size_t)row * DIM);
    float s0 = b[0], s1 = b[1];
    #pragma unroll
    for (int k4 = 0; k4 < 32; ++k4) {
        float4 v = a4[k4];
        int k = k4 * 4;
        s0 += v.x * Ws[(k + 0) * 2] + v.y * Ws[(k + 1) * 2] + v.z * Ws[(k + 2) * 2] + v.w * Ws[(k + 3) * 2];
        s1 += v.x * Ws[(k + 0) * 2 + 1] + v.y * Ws[(k + 1) * 2 + 1] + v.z * Ws[(k + 2) * 2 + 1] + v.w * Ws[(k + 3) * 2 + 1];
    }
    C[(size_t)row * 2 + 0] = fmaxf(s0, 0.f);
    C[(size_t)row * 2 + 1] = fmaxf(s1, 0.f);
}

// ---------------- BN stats: stats[0..C)=sum, stats[C..2C)=sumsq ----------------
template<int C>
__global__ __launch_bounds__(256) void stats_kernel(const float* __restrict__ h, int M,
                                                    float* __restrict__ stats) {
    __shared__ float ssum[256];
    __shared__ float ssq[256];
    const int tid = threadIdx.x;
    const int col = tid & (C - 1);
    const int rpb = 256 / C;
    float sum = 0.f, sq = 0.f;
    for (int row = blockIdx.x * rpb + tid / C; row < M; row += gridDim.x * rpb) {
        float v = h[(size_t)row * C + col];
        sum += v; sq += v * v;
    }
    ssum[tid] = sum; ssq[tid] = sq;
    __syncthreads();
    for (int s = 128; s >= C; s >>= 1) {
        if (tid < s) { ssum[tid] += ssum[tid + s]; ssq[tid] += ssq[tid + s]; }
        __syncthreads();
    }
    if (tid < C) {
        atomicAdd(&stats[tid], ssum[tid]);
        atomicAdd(&stats[C + tid], ssq[tid]);
    }
}

// finalize: stats -> scale/shift in place
template<int C>
__global__ __launch_bounds__(256) void bn_finalize_kernel(float* __restrict__ ss,
                                                          const float* __restrict__ g,
                                                          const float* __restrict__ be,
                                                          float invM) {
    int c = threadIdx.x;
    if (c < C) {
        float mean = ss[c] * invM;
        float var = ss[C + c] * invM - mean * mean;
        float sc = rsqrtf(var + BN_EPS) * g[c];
        ss[c] = sc;
        ss[C + c] = be[c] - mean * sc;
    }
}

// apply: y = h * scale[col] + shift[col]
template<int C>
__global__ __launch_bounds__(256) void bn_apply_kernel(const float* __restrict__ h,
                                                       const float* __restrict__ ss,
                                                       float* __restrict__ y, int n4) {
    int gid = blockIdx.x * 256 + threadIdx.x;
    if (gid >= n4) return;
    float4 v = ((const float4*)h)[gid];
    int base = gid * 4;
    float o[4] = {v.x, v.y, v.z, v.w};
    #pragma unroll
    for (int j = 0; j < 4; ++j) {
        int col = (base + j) & (C - 1);
        o[j] = o[j] * ss[col] + ss[C + col];
    }
    ((float4*)y)[gid] = make_float4(o[0], o[1], o[2], o[3]);
}

extern "C" void kernel_launch(void* const* d_in, const int* in_sizes, int n_in,
                              void* d_out, int out_size, void* d_ws, size_t ws_size,
                              hipStream_t stream) {
    const float* x   = (const float*)d_in[0];
    const int*   ei  = (const int*)d_in[1];
    const float* w11 = (const float*)d_in[2];
    const float* b11 = (const float*)d_in[3];
    const float* w12 = (const float*)d_in[4];
    const float* b12 = (const float*)d_in[5];
    const float* g1  = (const float*)d_in[6];
    const float* be1 = (const float*)d_in[7];
    const float* w21 = (const float*)d_in[8];
    const float* b21 = (const float*)d_in[9];
    const float* w22 = (const float*)d_in[10];
    const float* b22 = (const float*)d_in[11];
    const float* g2  = (const float*)d_in[12];
    const float* be2 = (const float*)d_in[13];

    const int M  = N_NODES;
    const int nE = in_sizes[1] / 2;
    const int* src = ei;
    const int* dst = ei + nE;

    const size_t SZ = (size_t)M * DIM;      // 6.4M floats
    float* agg    = (float*)d_ws;
    float* hmid   = agg + SZ;
    float* h1     = hmid + SZ;
    float* h2     = h1 + SZ;                // M*2 floats
    float* stats1 = h2 + (size_t)M * 2;     // 256 floats
    float* stats2 = stats1 + 256;           // 4 floats
    float* out    = (float*)d_out;

    const int mm_grid  = (M + 63) / 64;
    const int agg_grid = (nE * 32 + 255) / 256;
    const int n4_feat  = (int)(SZ / 4);
    const float invM = 1.0f / (float)M;

    // ---- layer 1 ----
    zero4_kernel<<<(n4_feat + 255) / 256, 256, 0, stream>>>((float4*)agg, n4_feat);
    zero4_kernel<<<1, 256, 0, stream>>>((float4*)stats1, 65);   // stats1(256) + stats2(4)
    agg_kernel<<<agg_grid, 256, 0, stream>>>(x, src, dst, agg, nE);
    mm_kernel<true, true><<<mm_grid, 256, 0, stream>>>(x, agg, w11, b11, hmid, M);
    mm_kernel<true, false><<<mm_grid, 256, 0, stream>>>(hmid, nullptr, w12, b12, h1, M);
    stats_kernel<128><<<512, 256, 0, stream>>>(h1, M, stats1);
    bn_finalize_kernel<128><<<1, 256, 0, stream>>>(stats1, g1, be1, invM);
    bn_apply_kernel<128><<<(n4_feat + 255) / 256, 256, 0, stream>>>(h1, stats1, h1, n4_feat);

    // ---- layer 2 ----
    zero4_kernel<<<(n4_feat + 255) / 256, 256, 0, stream>>>((float4*)agg, n4_feat);
    agg_kernel<<<agg_grid, 256, 0, stream>>>(h1, src, dst, agg, nE);
    mm_kernel<true, true><<<mm_grid, 256, 0, stream>>>(h1, agg, w21, b21, hmid, M);
    mm2out_kernel<<<(M + 255) / 256, 256, 0, stream>>>(hmid, w22, b22, h2, M);
    stats_kernel<2><<<128, 256, 0, stream>>>(h2, M, stats2);
    bn_finalize_kernel<2><<<1, 256, 0, stream>>>(stats2, g2, be2, invM);
    bn_apply_kernel<2><<<(M * 2 / 4 + 255) / 256, 256, 0, stream>>>(h2, stats2, out, M * 2 / 4);
}

// Round 2
// 672.883 us; speedup vs baseline: 8.2167x; 8.2167x over previous
//
#include <hip/hip_runtime.h>

#define N_NODES 50000
#define DIM 128
#define BN_EPS 1e-5f

// ---------------- zero ----------------
__global__ __launch_bounds__(256) void zero4_kernel(float4* __restrict__ p, int n4) {
    int i = blockIdx.x * 256 + threadIdx.x;
    if (i < n4) p[i] = make_float4(0.f, 0.f, 0.f, 0.f);
}

// ---------------- CSR build: histogram ----------------
__global__ __launch_bounds__(256) void hist_kernel(const int* __restrict__ dst, int nE,
                                                   int* __restrict__ deg) {
    int i = blockIdx.x * 256 + threadIdx.x;
    if (i < nE) atomicAdd(&deg[dst[i]], 1);
}

// ---------------- CSR build: single-block exclusive scan ----------------
__global__ __launch_bounds__(1024) void scan_kernel(const int* __restrict__ deg,
                                                    int* __restrict__ rowptr,
                                                    int* __restrict__ cursor, int n) {
    __shared__ int tsum[1024];
    const int tid = threadIdx.x;
    const int chunk = (n + 1023) / 1024;
    const int lo = tid * chunk;
    const int hi = min(lo + chunk, n);
    int s = 0;
    for (int i = lo; i < hi; ++i) s += deg[i];
    tsum[tid] = s;
    __syncthreads();
    for (int d = 1; d < 1024; d <<= 1) {
        int v = (tid >= d) ? tsum[tid - d] : 0;
        __syncthreads();
        tsum[tid] += v;
        __syncthreads();
    }
    int base = (tid == 0) ? 0 : tsum[tid - 1];
    for (int i = lo; i < hi; ++i) {
        rowptr[i] = base;
        cursor[i] = base;
        base += deg[i];
    }
    if (hi == n) rowptr[n] = base;
}

// ---------------- CSR build: scatter src into perm ----------------
__global__ __launch_bounds__(256) void scatter_kernel(const int* __restrict__ src,
                                                      const int* __restrict__ dst,
                                                      int* __restrict__ cursor,
                                                      int* __restrict__ perm, int nE) {
    int i = blockIdx.x * 256 + threadIdx.x;
    if (i < nE) {
        int p = atomicAdd(&cursor[dst[i]], 1);
        perm[p] = src[i];
    }
}

// ---------------- gather-aggregate: h[n] = x[n] + sum_{s in N(n)} x[s] ----------------
// one 64-lane wave per node, float2 per lane
__global__ __launch_bounds__(256) void gather_agg_kernel(const float* __restrict__ x,
                                                         const int* __restrict__ rowptr,
                                                         const int* __restrict__ perm,
                                                         float* __restrict__ h, int M) {
    const int node = blockIdx.x * 4 + (threadIdx.x >> 6);
    if (node >= M) return;
    const int lane = threadIdx.x & 63;
    const float2* __restrict__ x2 = (const float2*)x;
    float2 acc = x2[(size_t)node * 64 + lane];
    const int beg = rowptr[node];
    const int end = rowptr[node + 1];
    int e = beg;
    for (; e + 4 <= end; e += 4) {
        int s0 = perm[e + 0];
        int s1 = perm[e + 1];
        int s2 = perm[e + 2];
        int s3 = perm[e + 3];
        float2 v0 = x2[(size_t)s0 * 64 + lane];
        float2 v1 = x2[(size_t)s1 * 64 + lane];
        float2 v2 = x2[(size_t)s2 * 64 + lane];
        float2 v3 = x2[(size_t)s3 * 64 + lane];
        acc.x += v0.x; acc.y += v0.y;
        acc.x += v1.x; acc.y += v1.y;
        acc.x += v2.x; acc.y += v2.y;
        acc.x += v3.x; acc.y += v3.y;
    }
    for (; e < end; ++e) {
        int s = perm[e];
        float2 v = x2[(size_t)s * 64 + lane];
        acc.x += v.x; acc.y += v.y;
    }
    ((float2*)h)[(size_t)node * 64 + lane] = acc;
}

// ---------------- C[M x 128] = relu?(A @ W + b) ----------------
// block 256, tile 64 rows x 128 cols, per-thread 8x4
template<bool RELU>
__global__ __launch_bounds__(256) void mm_kernel(const float* __restrict__ A,
                                                 const float* __restrict__ W,
                                                 const float* __restrict__ b,
                                                 float* __restrict__ C, int M) {
    __shared__ float As[64][33];
    __shared__ float Ws[32][128];
    const int tid = threadIdx.x;
    const int tx = tid & 31;   // col group: cols tx*4..tx*4+3
    const int ty = tid >> 5;   // row group: rows ty*8..ty*8+7
    const int row0 = blockIdx.x * 64;
    float acc[8][4] = {};

    for (int kb = 0; kb < 128; kb += 32) {
        // stage A chunk: 64 rows x 32 cols
        {
            const int c4 = tid & 7;
            const int rr = tid >> 3;
            #pragma unroll
            for (int p = 0; p < 2; ++p) {
                int row = row0 + rr + p * 32;
                float4 v = make_float4(0.f, 0.f, 0.f, 0.f);
                if (row < M) v = ((const float4*)(A + (size_t)row * DIM + kb))[c4];
                As[rr + p * 32][c4 * 4 + 0] = v.x;
                As[rr + p * 32][c4 * 4 + 1] = v.y;
                As[rr + p * 32][c4 * 4 + 2] = v.z;
                As[rr + p * 32][c4 * 4 + 3] = v.w;
            }
        }
        // stage W chunk: 32 rows x 128 cols
        {
            const int wc4 = tid & 31;
            const int wr = tid >> 5;
            #pragma unroll
            for (int p = 0; p < 4; ++p) {
                float4 v = ((const float4*)(W + (size_t)(kb + wr + p * 8) * DIM))[wc4];
                *((float4*)&Ws[wr + p * 8][wc4 * 4]) = v;
            }
        }
        __syncthreads();
        #pragma unroll
        for (int kk = 0; kk < 32; ++kk) {
            const float4 wv = *((const float4*)&Ws[kk][tx * 4]);
            #pragma unroll
            for (int r = 0; r < 8; ++r) {
                float a = As[ty * 8 + r][kk];
                acc[r][0] += a * wv.x;
                acc[r][1] += a * wv.y;
                acc[r][2] += a * wv.z;
                acc[r][3] += a * wv.w;
            }
        }
        __syncthreads();
    }

    const float4 bv = *((const float4*)&b[tx * 4]);
    #pragma unroll
    for (int r = 0; r < 8; ++r) {
        int row = row0 + ty * 8 + r;
        if (row < M) {
            float4 o;
            o.x = acc[r][0] + bv.x;
            o.y = acc[r][1] + bv.y;
            o.z = acc[r][2] + bv.z;
            o.w = acc[r][3] + bv.w;
            if (RELU) {
                o.x = fmaxf(o.x, 0.f); o.y = fmaxf(o.y, 0.f);
                o.z = fmaxf(o.z, 0.f); o.w = fmaxf(o.w, 0.f);
            }
            ((float4*)(C + (size_t)row * DIM))[tx] = o;
        }
    }
}

// ---------------- C[M x 2] = relu(A @ W(128x2) + b) ----------------
__global__ __launch_bounds__(256) void mm2out_kernel(const float* __restrict__ A,
                                                     const float* __restrict__ W,
                                                     const float* __restrict__ b,
                                                     float* __restrict__ C, int M) {
    __shared__ float Ws[256];
    int tid = threadIdx.x;
    Ws[tid] = W[tid];
    __syncthreads();
    int row = blockIdx.x * 256 + tid;
    if (row >= M) return;
    const float4* a4 = (const float4*)(A + (size_t)row * DIM);
    float s0 = b[0], s1 = b[1];
    #pragma unroll
    for (int k4 = 0; k4 < 32; ++k4) {
        float4 v = a4[k4];
        int k = k4 * 4;
        s0 += v.x * Ws[(k + 0) * 2] + v.y * Ws[(k + 1) * 2] + v.z * Ws[(k + 2) * 2] + v.w * Ws[(k + 3) * 2];
        s1 += v.x * Ws[(k + 0) * 2 + 1] + v.y * Ws[(k + 1) * 2 + 1] + v.z * Ws[(k + 2) * 2 + 1] + v.w * Ws[(k + 3) * 2 + 1];
    }
    C[(size_t)row * 2 + 0] = fmaxf(s0, 0.f);
    C[(size_t)row * 2 + 1] = fmaxf(s1, 0.f);
}

// ---------------- BN stats: stats[0..C)=sum, stats[C..2C)=sumsq ----------------
template<int C>
__global__ __launch_bounds__(256) void stats_kernel(const float* __restrict__ h, int M,
                                                    float* __restrict__ stats) {
    __shared__ float ssum[256];
    __shared__ float ssq[256];
    const int tid = threadIdx.x;
    const int col = tid & (C - 1);
    const int rpb = 256 / C;
    float sum = 0.f, sq = 0.f;
    for (int row = blockIdx.x * rpb + tid / C; row < M; row += gridDim.x * rpb) {
        float v = h[(size_t)row * C + col];
        sum += v; sq += v * v;
    }
    ssum[tid] = sum; ssq[tid] = sq;
    __syncthreads();
    for (int s = 128; s >= C; s >>= 1) {
        if (tid < s) { ssum[tid] += ssum[tid + s]; ssq[tid] += ssq[tid + s]; }
        __syncthreads();
    }
    if (tid < C) {
        atomicAdd(&stats[tid], ssum[tid]);
        atomicAdd(&stats[C + tid], ssq[tid]);
    }
}

// finalize: stats -> scale/shift in place
template<int C>
__global__ __launch_bounds__(256) void bn_finalize_kernel(float* __restrict__ ss,
                                                          const float* __restrict__ g,
                                                          const float* __restrict__ be,
                                                          float invM) {
    int c = threadIdx.x;
    if (c < C) {
        float mean = ss[c] * invM;
        float var = ss[C + c] * invM - mean * mean;
        float sc = rsqrtf(var + BN_EPS) * g[c];
        ss[c] = sc;
        ss[C + c] = be[c] - mean * sc;
    }
}

// apply: y = h * scale[col] + shift[col]
template<int C>
__global__ __launch_bounds__(256) void bn_apply_kernel(const float* __restrict__ h,
                                                       const float* __restrict__ ss,
                                                       float* __restrict__ y, int n4) {
    int gid = blockIdx.x * 256 + threadIdx.x;
    if (gid >= n4) return;
    float4 v = ((const float4*)h)[gid];
    int base = gid * 4;
    float o[4] = {v.x, v.y, v.z, v.w};
    #pragma unroll
    for (int j = 0; j < 4; ++j) {
        int col = (base + j) & (C - 1);
        o[j] = o[j] * ss[col] + ss[C + col];
    }
    ((float4*)y)[gid] = make_float4(o[0], o[1], o[2], o[3]);
}

extern "C" void kernel_launch(void* const* d_in, const int* in_sizes, int n_in,
                              void* d_out, int out_size, void* d_ws, size_t ws_size,
                              hipStream_t stream) {
    const float* x   = (const float*)d_in[0];
    const int*   ei  = (const int*)d_in[1];
    const float* w11 = (const float*)d_in[2];
    const float* b11 = (const float*)d_in[3];
    const float* w12 = (const float*)d_in[4];
    const float* b12 = (const float*)d_in[5];
    const float* g1  = (const float*)d_in[6];
    const float* be1 = (const float*)d_in[7];
    const float* w21 = (const float*)d_in[8];
    const float* b21 = (const float*)d_in[9];
    const float* w22 = (const float*)d_in[10];
    const float* b22 = (const float*)d_in[11];
    const float* g2  = (const float*)d_in[12];
    const float* be2 = (const float*)d_in[13];

    const int M  = N_NODES;
    const int nE = in_sizes[1] / 2;
    const int* src = ei;
    const int* dst = ei + nE;

    const size_t SZ = (size_t)M * DIM;      // 6.4M floats
    float* buf1   = (float*)d_ws;           // 25.6 MB
    float* buf2   = buf1 + SZ;              // 25.6 MB
    float* h2     = buf2 + SZ;              // M*2 floats
    float* stats1 = h2 + (size_t)M * 2;     // 256 floats
    float* stats2 = stats1 + 256;           // 4 floats (+pad to 16)
    int*   deg    = (int*)(stats2 + 16);    // M ints
    int*   rowptr = deg + M;                // M+1 ints
    int*   cursor = rowptr + M + 1;         // M ints
    int*   perm   = cursor + M;             // nE ints

    const int mm_grid   = (M + 63) / 64;
    const int edge_grid = (nE + 255) / 256;
    const int agg_grid  = (M + 3) / 4;
    const int n4_feat   = (int)(SZ / 4);
    const float invM = 1.0f / (float)M;

    // ---- CSR build (once, reused by both layers) ----
    zero4_kernel<<<(M / 4 + 255) / 256, 256, 0, stream>>>((float4*)deg, M / 4);
    hist_kernel<<<edge_grid, 256, 0, stream>>>(dst, nE, deg);
    scan_kernel<<<1, 1024, 0, stream>>>(deg, rowptr, cursor, M);
    scatter_kernel<<<edge_grid, 256, 0, stream>>>(src, dst, cursor, perm, nE);
    zero4_kernel<<<1, 256, 0, stream>>>((float4*)stats1, 65);   // stats1(256)+stats2(4)

    // ---- layer 1 ----
    gather_agg_kernel<<<agg_grid, 256, 0, stream>>>(x, rowptr, perm, buf1, M);
    mm_kernel<true><<<mm_grid, 256, 0, stream>>>(buf1, w11, b11, buf2, M);
    mm_kernel<true><<<mm_grid, 256, 0, stream>>>(buf2, w12, b12, buf1, M);
    stats_kernel<128><<<512, 256, 0, stream>>>(buf1, M, stats1);
    bn_finalize_kernel<128><<<1, 256, 0, stream>>>(stats1, g1, be1, invM);
    bn_apply_kernel<128><<<(n4_feat + 255) / 256, 256, 0, stream>>>(buf1, stats1, buf1, n4_feat);

    // ---- layer 2 ----
    gather_agg_kernel<<<agg_grid, 256, 0, stream>>>(buf1, rowptr, perm, buf2, M);
    mm_kernel<true><<<mm_grid, 256, 0, stream>>>(buf2, w21, b21, buf1, M);
    mm2out_kernel<<<(M + 255) / 256, 256, 0, stream>>>(buf1, w22, b22, h2, M);
    stats_kernel<2><<<128, 256, 0, stream>>>(h2, M, stats2);
    bn_finalize_kernel<2><<<1, 256, 0, stream>>>(stats2, g2, be2, invM);
    bn_apply_kernel<2><<<(M * 2 / 4 + 255) / 256, 256, 0, stream>>>(h2, stats2, (float*)d_out, M * 2 / 4);
}

// Round 3
// 537.861 us; speedup vs baseline: 10.2794x; 1.2510x over previous
//
#include <hip/hip_runtime.h>

#define N_NODES 50000
#define DIM 128
#define BN_EPS 1e-5f

using short8 = __attribute__((ext_vector_type(8))) short;
using f32x4  = __attribute__((ext_vector_type(4))) float;

__device__ __forceinline__ float b2f(ushort h) { return __uint_as_float(((uint)h) << 16); }
__device__ __forceinline__ ushort f2b(float f) {
    uint u = __float_as_uint(f);
    u += 0x7FFF + ((u >> 16) & 1);   // round-to-nearest-even
    return (ushort)(u >> 16);
}

// ---------------- zero ----------------
__global__ __launch_bounds__(256) void zero4_kernel(float4* __restrict__ p, int n4) {
    int i = blockIdx.x * 256 + threadIdx.x;
    if (i < n4) p[i] = make_float4(0.f, 0.f, 0.f, 0.f);
}

// ---------------- CSR build ----------------
__global__ __launch_bounds__(256) void hist_kernel(const int* __restrict__ dst, int nE,
                                                   int* __restrict__ deg) {
    int i = blockIdx.x * 256 + threadIdx.x;
    if (i < nE) atomicAdd(&deg[dst[i]], 1);
}

__global__ __launch_bounds__(1024) void scan_kernel(const int* __restrict__ deg,
                                                    int* __restrict__ rowptr,
                                                    int* __restrict__ cursor, int n) {
    __shared__ int tsum[1024];
    const int tid = threadIdx.x;
    const int chunk = (n + 1023) / 1024;
    const int lo = tid * chunk;
    const int hi = min(lo + chunk, n);
    int s = 0;
    for (int i = lo; i < hi; ++i) s += deg[i];
    tsum[tid] = s;
    __syncthreads();
    for (int d = 1; d < 1024; d <<= 1) {
        int v = (tid >= d) ? tsum[tid - d] : 0;
        __syncthreads();
        tsum[tid] += v;
        __syncthreads();
    }
    int base = (tid == 0) ? 0 : tsum[tid - 1];
    for (int i = lo; i < hi; ++i) {
        rowptr[i] = base;
        cursor[i] = base;
        base += deg[i];
    }
    if (hi == n) rowptr[n] = base;
}

__global__ __launch_bounds__(256) void scatter_kernel(const int* __restrict__ src,
                                                      const int* __restrict__ dst,
                                                      int* __restrict__ cursor,
                                                      ushort* __restrict__ perm, int nE) {
    int i = blockIdx.x * 256 + threadIdx.x;
    if (i < nE) {
        int p = atomicAdd(&cursor[dst[i]], 1);
        perm[p] = (ushort)src[i];
    }
}

// ---------------- converts ----------------
__global__ __launch_bounds__(256) void convert_x_kernel(const float4* __restrict__ x4,
                                                        ushort4* __restrict__ xb, int n4) {
    int i = blockIdx.x * 256 + threadIdx.x;
    if (i < n4) {
        float4 v = x4[i];
        ushort4 o;
        o.x = f2b(v.x); o.y = f2b(v.y); o.z = f2b(v.z); o.w = f2b(v.w);
        xb[i] = o;
    }
}

// transpose+convert three 128x128 weights: Wt[n][k] = W[k][n]
__global__ __launch_bounds__(256) void convert_w_kernel(const float* __restrict__ w0,
                                                        const float* __restrict__ w1,
                                                        const float* __restrict__ w2,
                                                        ushort* __restrict__ o0,
                                                        ushort* __restrict__ o1,
                                                        ushort* __restrict__ o2) {
    const float* W = (blockIdx.y == 0) ? w0 : (blockIdx.y == 1) ? w1 : w2;
    ushort* O = (blockIdx.y == 0) ? o0 : (blockIdx.y == 1) ? o1 : o2;
    int id = blockIdx.x * 256 + threadIdx.x;   // 0..16383
    int k = id >> 7, n = id & 127;
    O[n * 128 + k] = f2b(W[id]);
}

// ---------------- gather-aggregate (bf16): h[n] = x[n] + sum_{s in N(n)} x[s] ----------------
// one 64-lane wave per node; each lane handles 2 features packed in a uint
__global__ __launch_bounds__(256) void gather_agg_kernel(const uint* __restrict__ xb,
                                                         const int* __restrict__ rowptr,
                                                         const ushort* __restrict__ perm,
                                                         uint* __restrict__ out, int M) {
    const int node = blockIdx.x * 4 + (threadIdx.x >> 6);
    if (node >= M) return;
    const int lane = threadIdx.x & 63;
    uint v = xb[(size_t)node * 64 + lane];
    float ax = __uint_as_float(v << 16);
    float ay = __uint_as_float(v & 0xffff0000u);
    const int beg = rowptr[node], end = rowptr[node + 1];
    int e = beg;
    for (; e + 4 <= end; e += 4) {
        int s0 = perm[e + 0];
        int s1 = perm[e + 1];
        int s2 = perm[e + 2];
        int s3 = perm[e + 3];
        uint v0 = xb[(size_t)s0 * 64 + lane];
        uint v1 = xb[(size_t)s1 * 64 + lane];
        uint v2 = xb[(size_t)s2 * 64 + lane];
        uint v3 = xb[(size_t)s3 * 64 + lane];
        ax += __uint_as_float(v0 << 16); ay += __uint_as_float(v0 & 0xffff0000u);
        ax += __uint_as_float(v1 << 16); ay += __uint_as_float(v1 & 0xffff0000u);
        ax += __uint_as_float(v2 << 16); ay += __uint_as_float(v2 & 0xffff0000u);
        ax += __uint_as_float(v3 << 16); ay += __uint_as_float(v3 & 0xffff0000u);
    }
    for (; e < end; ++e) {
        uint vv = xb[(size_t)perm[e] * 64 + lane];
        ax += __uint_as_float(vv << 16); ay += __uint_as_float(vv & 0xffff0000u);
    }
    out[(size_t)node * 64 + lane] = ((uint)f2b(ay) << 16) | (uint)f2b(ax);
}

// ---------------- MFMA matmul: C[M x 128] = relu(A @ W + b), bf16 in, bf16 out ----------------
// block 256 = 4 waves, each wave 16 rows x 128 cols; no LDS.
__global__ __launch_bounds__(256) void mfma_mm_kernel(const ushort* __restrict__ A,
                                                      const ushort* __restrict__ Wt, // Wt[n][k]
                                                      const float* __restrict__ b,
                                                      ushort* __restrict__ C, int M) {
    const int wid = threadIdx.x >> 6;
    const int lane = threadIdx.x & 63;
    const int row0 = blockIdx.x * 64 + wid * 16;
    const int r = lane & 15;
    const int kg = lane >> 4;

    const int arow = min(row0 + r, M - 1);
    const ushort* Arow = A + (size_t)arow * 128 + kg * 8;
    short8 a[4];
    #pragma unroll
    for (int kb = 0; kb < 4; ++kb)
        a[kb] = *(const short8*)(Arow + kb * 32);

    #pragma unroll
    for (int c = 0; c < 8; ++c) {
        f32x4 acc = {0.f, 0.f, 0.f, 0.f};
        const ushort* Wcol = Wt + (size_t)(c * 16 + r) * 128 + kg * 8;
        #pragma unroll
        for (int kb = 0; kb < 4; ++kb) {
            short8 bb = *(const short8*)(Wcol + kb * 32);
            acc = __builtin_amdgcn_mfma_f32_16x16x32_bf16(a[kb], bb, acc, 0, 0, 0);
        }
        float bias = b[c * 16 + r];
        #pragma unroll
        for (int j = 0; j < 4; ++j) {
            int orow = row0 + kg * 4 + j;
            if (orow < M) {
                float v = fmaxf(acc[j] + bias, 0.f);
                C[(size_t)orow * 128 + c * 16 + r] = f2b(v);
            }
        }
    }
}

// ---------------- C[M x 2] = relu(A(bf16) @ W(128x2,f32) + b) ----------------
__global__ __launch_bounds__(256) void mm2out_kernel(const ushort* __restrict__ A,
                                                     const float* __restrict__ W,
                                                     const float* __restrict__ b,
                                                     float* __restrict__ C, int M) {
    __shared__ float Ws[256];
    int tid = threadIdx.x;
    Ws[tid] = W[tid];
    __syncthreads();
    int row = blockIdx.x * 256 + tid;
    if (row >= M) return;
    const short8* a8 = (const short8*)(A + (size_t)row * 128);
    float s0 = b[0], s1 = b[1];
    #pragma unroll
    for (int k8 = 0; k8 < 16; ++k8) {
        short8 v = a8[k8];
        #pragma unroll
        for (int j = 0; j < 8; ++j) {
            float f = b2f((ushort)v[j]);
            int k = k8 * 8 + j;
            s0 += f * Ws[k * 2];
            s1 += f * Ws[k * 2 + 1];
        }
    }
    C[(size_t)row * 2 + 0] = fmaxf(s0, 0.f);
    C[(size_t)row * 2 + 1] = fmaxf(s1, 0.f);
}

// ---------------- BN stats (bf16 input) ----------------
__global__ __launch_bounds__(256) void stats128_kernel(const ushort* __restrict__ h, int M,
                                                       float* __restrict__ stats) {
    __shared__ float ssum[256];
    __shared__ float ssq[256];
    const int tid = threadIdx.x;
    const int col = tid & 127;
    float sum = 0.f, sq = 0.f;
    for (int row = blockIdx.x * 2 + (tid >> 7); row < M; row += gridDim.x * 2) {
        float v = b2f(h[(size_t)row * 128 + col]);
        sum += v; sq += v * v;
    }
    ssum[tid] = sum; ssq[tid] = sq;
    __syncthreads();
    if (tid < 128) { ssum[tid] += ssum[tid + 128]; ssq[tid] += ssq[tid + 128]; }
    __syncthreads();
    if (tid < 128) {
        atomicAdd(&stats[tid], ssum[tid]);
        atomicAdd(&stats[128 + tid], ssq[tid]);
    }
}

__global__ __launch_bounds__(256) void stats2_kernel(const float* __restrict__ h, int M,
                                                     float* __restrict__ stats) {
    __shared__ float ssum[256];
    __shared__ float ssq[256];
    const int tid = threadIdx.x;
    const int col = tid & 1;
    float sum = 0.f, sq = 0.f;
    for (int row = blockIdx.x * 128 + (tid >> 1); row < M; row += gridDim.x * 128) {
        float v = h[(size_t)row * 2 + col];
        sum += v; sq += v * v;
    }
    ssum[tid] = sum; ssq[tid] = sq;
    __syncthreads();
    for (int s = 128; s >= 2; s >>= 1) {
        if (tid < s) { ssum[tid] += ssum[tid + s]; ssq[tid] += ssq[tid + s]; }
        __syncthreads();
    }
    if (tid < 2) {
        atomicAdd(&stats[tid], ssum[tid]);
        atomicAdd(&stats[2 + tid], ssq[tid]);
    }
}

template<int C>
__global__ __launch_bounds__(256) void bn_finalize_kernel(float* __restrict__ ss,
                                                          const float* __restrict__ g,
                                                          const float* __restrict__ be,
                                                          float invM) {
    int c = threadIdx.x;
    if (c < C) {
        float mean = ss[c] * invM;
        float var = ss[C + c] * invM - mean * mean;
        float sc = rsqrtf(var + BN_EPS) * g[c];
        ss[c] = sc;
        ss[C + c] = be[c] - mean * sc;
    }
}

// bf16 in-place BN apply: 8 features (one uint4) per thread
__global__ __launch_bounds__(256) void bn_apply128_kernel(uint4* __restrict__ h,
                                                          const float* __restrict__ ss, int n16) {
    int gid = blockIdx.x * 256 + threadIdx.x;
    if (gid >= n16) return;
    uint4 v = h[gid];
    int base = (gid * 8) & 127;
    uint w[4] = {v.x, v.y, v.z, v.w};
    #pragma unroll
    for (int p = 0; p < 4; ++p) {
        int c0 = base + p * 2;
        float lo = __uint_as_float(w[p] << 16) * ss[c0] + ss[128 + c0];
        float hi = __uint_as_float(w[p] & 0xffff0000u) * ss[c0 + 1] + ss[128 + c0 + 1];
        w[p] = ((uint)f2b(hi) << 16) | (uint)f2b(lo);
    }
    h[gid] = make_uint4(w[0], w[1], w[2], w[3]);
}

__global__ __launch_bounds__(256) void bn_apply2_kernel(const float* __restrict__ h,
                                                        const float* __restrict__ ss,
                                                        float* __restrict__ y, int n4) {
    int gid = blockIdx.x * 256 + threadIdx.x;
    if (gid >= n4) return;
    float4 v = ((const float4*)h)[gid];
    float4 o;
    o.x = v.x * ss[0] + ss[2];
    o.y = v.y * ss[1] + ss[3];
    o.z = v.z * ss[0] + ss[2];
    o.w = v.w * ss[1] + ss[3];
    ((float4*)y)[gid] = o;
}

extern "C" void kernel_launch(void* const* d_in, const int* in_sizes, int n_in,
                              void* d_out, int out_size, void* d_ws, size_t ws_size,
                              hipStream_t stream) {
    const float* x   = (const float*)d_in[0];
    const int*   ei  = (const int*)d_in[1];
    const float* w11 = (const float*)d_in[2];
    const float* b11 = (const float*)d_in[3];
    const float* w12 = (const float*)d_in[4];
    const float* b12 = (const float*)d_in[5];
    const float* g1  = (const float*)d_in[6];
    const float* be1 = (const float*)d_in[7];
    const float* w21 = (const float*)d_in[8];
    const float* b21 = (const float*)d_in[9];
    const float* w22 = (const float*)d_in[10];
    const float* b22 = (const float*)d_in[11];
    const float* g2  = (const float*)d_in[12];
    const float* be2 = (const float*)d_in[13];

    const int M  = N_NODES;
    const int nE = in_sizes[1] / 2;
    const int* src = ei;
    const int* dst = ei + nE;

    const size_t RBYTES = (size_t)50048 * 128 * 2;   // padded bf16 feature buffer
    char* w = (char*)d_ws;
    ushort* xb   = (ushort*)w;  w += RBYTES;
    ushort* gbuf = (ushort*)w;  w += RBYTES;
    ushort* tbuf = (ushort*)w;  w += RBYTES;
    ushort* hbuf = (ushort*)w;  w += RBYTES;
    float* h2    = (float*)w;   w += 400128;
    float* stats1= (float*)w;   w += 256 * 4;
    float* stats2= (float*)w;   w += 16 * 4;
    ushort* wt11 = (ushort*)w;  w += 32768;
    ushort* wt12 = (ushort*)w;  w += 32768;
    ushort* wt21 = (ushort*)w;  w += 32768;
    int* deg     = (int*)w;     w += (size_t)M * 4;
    int* rowptr  = (int*)w;     w += (size_t)(M + 4) * 4;
    int* cursor  = (int*)w;     w += (size_t)M * 4;
    ushort* perm = (ushort*)w;

    const int edge_grid = (nE + 255) / 256;
    const int agg_grid  = (M + 3) / 4;
    const int mm_grid   = (M + 63) / 64;
    const float invM = 1.0f / (float)M;

    // ---- CSR build + converts ----
    zero4_kernel<<<(M / 4 + 255) / 256, 256, 0, stream>>>((float4*)deg, M / 4);
    hist_kernel<<<edge_grid, 256, 0, stream>>>(dst, nE, deg);
    convert_x_kernel<<<(M * 32 + 255) / 256, 256, 0, stream>>>((const float4*)x, (ushort4*)xb, M * 32);
    convert_w_kernel<<<dim3(64, 3), 256, 0, stream>>>(w11, w12, w21, wt11, wt12, wt21);
    zero4_kernel<<<1, 256, 0, stream>>>((float4*)stats1, 68);   // stats1(256)+stats2(16)
    scan_kernel<<<1, 1024, 0, stream>>>(deg, rowptr, cursor, M);
    scatter_kernel<<<edge_grid, 256, 0, stream>>>(src, dst, cursor, perm, nE);

    // ---- layer 1 ----
    gather_agg_kernel<<<agg_grid, 256, 0, stream>>>((const uint*)xb, rowptr, perm, (uint*)gbuf, M);
    mfma_mm_kernel<<<mm_grid, 256, 0, stream>>>(gbuf, wt11, b11, tbuf, M);
    mfma_mm_kernel<<<mm_grid, 256, 0, stream>>>(tbuf, wt12, b12, hbuf, M);
    stats128_kernel<<<512, 256, 0, stream>>>(hbuf, M, stats1);
    bn_finalize_kernel<128><<<1, 256, 0, stream>>>(stats1, g1, be1, invM);
    bn_apply128_kernel<<<(M * 16 + 255) / 256, 256, 0, stream>>>((uint4*)hbuf, stats1, M * 16);

    // ---- layer 2 ----
    gather_agg_kernel<<<agg_grid, 256, 0, stream>>>((const uint*)hbuf, rowptr, perm, (uint*)gbuf, M);
    mfma_mm_kernel<<<mm_grid, 256, 0, stream>>>(gbuf, wt21, b21, tbuf, M);
    mm2out_kernel<<<(M + 255) / 256, 256, 0, stream>>>(tbuf, w22, b22, h2, M);
    stats2_kernel<<<128, 256, 0, stream>>>(h2, M, stats2);
    bn_finalize_kernel<2><<<1, 256, 0, stream>>>(stats2, g2, be2, invM);
    bn_apply2_kernel<<<(M / 2 + 255) / 256, 256, 0, stream>>>(h2, stats2, (float*)d_out, M / 2);
}

// Round 4
// 406.420 us; speedup vs baseline: 13.6039x; 1.3234x over previous
//
#include <hip/hip_runtime.h>

#define N_NODES 50000
#define BN_EPS 1e-5f
#define NBUCK 391
#define SUBCAP 768
#define ENTCAP 5120

using short8 = __attribute__((ext_vector_type(8))) short;
using f32x4  = __attribute__((ext_vector_type(4))) float;

__device__ __forceinline__ float b2f(ushort h) { return __uint_as_float(((uint)h) << 16); }
__device__ __forceinline__ ushort f2b(float f) {
    uint u = __float_as_uint(f);
    u += 0x7FFF + ((u >> 16) & 1);   // round-to-nearest-even
    return (ushort)(u >> 16);
}

// ---------------- zero ----------------
__global__ __launch_bounds__(256) void zero4_kernel(float4* __restrict__ p, int n4) {
    int i = blockIdx.x * 256 + threadIdx.x;
    if (i < n4) p[i] = make_float4(0.f, 0.f, 0.f, 0.f);
}

// ---------------- converts ----------------
__global__ __launch_bounds__(256) void convert_x_kernel(const float4* __restrict__ x4,
                                                        ushort4* __restrict__ xb, int n4) {
    int i = blockIdx.x * 256 + threadIdx.x;
    if (i < n4) {
        float4 v = x4[i];
        ushort4 o;
        o.x = f2b(v.x); o.y = f2b(v.y); o.z = f2b(v.z); o.w = f2b(v.w);
        xb[i] = o;
    }
}

// transpose+convert three 128x128 weights: Wt[n][k] = W[k][n]
__global__ __launch_bounds__(256) void convert_w_kernel(const float* __restrict__ w0,
                                                        const float* __restrict__ w1,
                                                        const float* __restrict__ w2,
                                                        ushort* __restrict__ o0,
                                                        ushort* __restrict__ o1,
                                                        ushort* __restrict__ o2) {
    const float* W = (blockIdx.y == 0) ? w0 : (blockIdx.y == 1) ? w1 : w2;
    ushort* O = (blockIdx.y == 0) ? o0 : (blockIdx.y == 1) ? o1 : o2;
    int id = blockIdx.x * 256 + threadIdx.x;   // 0..16383
    int k = id >> 7, n = id & 127;
    O[n * 128 + k] = f2b(W[id]);
}

// ---------------- CSR build pass A: XCD-local bucketing ----------------
// sub-bucket (b, g): b = dst>>7 (128 nodes/bucket), g = blockIdx&7 (XCD heuristic)
__global__ __launch_bounds__(256) void bucket_pass_kernel(const int* __restrict__ src,
                                                          const int* __restrict__ dst, int nE,
                                                          int* __restrict__ cnt,
                                                          uint* __restrict__ bdata) {
    const int g = blockIdx.x & 7;
    for (int i = blockIdx.x * 256 + threadIdx.x; i < nE; i += gridDim.x * 256) {
        int s = src[i], d = dst[i];
        int sb = (d >> 7) * 8 + g;
        int pos = atomicAdd(&cnt[sb], 1);
        if (pos < SUBCAP) bdata[(size_t)sb * SUBCAP + pos] = ((uint)(d & 127) << 16) | (uint)s;
    }
}

// ---------------- CSR build: bucket-base scan (1 block) ----------------
__global__ __launch_bounds__(512) void bucket_scan_kernel(const int* __restrict__ cnt,
                                                          int* __restrict__ base,
                                                          int* __restrict__ rowptr_end) {
    __shared__ int tot[512];
    const int b = threadIdx.x;
    int t = 0;
    if (b < NBUCK) {
        #pragma unroll
        for (int g = 0; g < 8; ++g) t += min(cnt[b * 8 + g], SUBCAP);
        t = min(t, ENTCAP);
    }
    tot[b] = t;
    __syncthreads();
    for (int d = 1; d < 512; d <<= 1) {
        int v = (b >= d) ? tot[b - d] : 0;
        __syncthreads();
        tot[b] += v;
        __syncthreads();
    }
    if (b < NBUCK) base[b] = tot[b] - t;
    if (b == NBUCK - 1) rowptr_end[0] = tot[b];
}

// ---------------- CSR build pass B: per-bucket LDS counting sort ----------------
__global__ __launch_bounds__(256) void csr_build_kernel(const int* __restrict__ cnt,
                                                        const int* __restrict__ base,
                                                        const uint* __restrict__ bdata,
                                                        int* __restrict__ rowptr,
                                                        ushort* __restrict__ perm, int M) {
    __shared__ uint ent[ENTCAP];
    __shared__ int hist[128];
    __shared__ int scn[128];
    __shared__ int cur[128];
    __shared__ int subbase[9];
    const int b = blockIdx.x;
    const int tid = threadIdx.x;
    if (tid == 0) {
        int o = 0;
        #pragma unroll
        for (int g = 0; g < 8; ++g) {
            subbase[g] = o;
            o = min(o + min(cnt[b * 8 + g], SUBCAP), ENTCAP);
        }
        subbase[8] = o;
    }
    if (tid < 128) hist[tid] = 0;
    __syncthreads();
    const int nb = subbase[8];
    for (int g = 0; g < 8; ++g) {
        const int s0 = subbase[g], n = subbase[g + 1] - s0;
        const uint* p = bdata + (size_t)(b * 8 + g) * SUBCAP;
        for (int i = tid; i < n; i += 256) ent[s0 + i] = p[i];
    }
    __syncthreads();
    for (int i = tid; i < nb; i += 256) atomicAdd(&hist[ent[i] >> 16], 1);
    __syncthreads();
    if (tid < 128) scn[tid] = hist[tid];
    __syncthreads();
    for (int d = 1; d < 128; d <<= 1) {
        int v = 0;
        if (tid < 128 && tid >= d) v = scn[tid - d];
        __syncthreads();
        if (tid < 128) scn[tid] += v;
        __syncthreads();
    }
    const int bb = base[b];
    if (tid < 128) {
        int ex = scn[tid] - hist[tid];   // exclusive scan
        cur[tid] = ex;
        int node = b * 128 + tid;
        if (node < M) rowptr[node] = bb + ex;
    }
    __syncthreads();
    for (int i = tid; i < nb; i += 256) {
        uint e = ent[i];
        int lp = atomicAdd(&cur[e >> 16], 1);
        perm[bb + lp] = (ushort)(e & 0xffffu);
    }
}

// ---------------- gather-aggregate (bf16), optional fused BN-apply of the input ----------------
// BN fold: sum_s BN(h[s]) + BN(h[n]) = (h[n]+sum h[s])*sc + (deg+1)*sh
template<bool BN>
__global__ __launch_bounds__(256) void gather_kernel(const uint* __restrict__ xb,
                                                     const int* __restrict__ rowptr,
                                                     const ushort* __restrict__ perm,
                                                     const float* __restrict__ ss,
                                                     uint* __restrict__ out, int M) {
    const int node = blockIdx.x * 4 + (threadIdx.x >> 6);
    if (node >= M) return;
    const int lane = threadIdx.x & 63;
    uint v = xb[(size_t)node * 64 + lane];
    float ax = __uint_as_float(v << 16);
    float ay = __uint_as_float(v & 0xffff0000u);
    const int beg = rowptr[node], end = rowptr[node + 1];
    int e = beg;
    for (; e + 4 <= end; e += 4) {
        int s0 = perm[e + 0];
        int s1 = perm[e + 1];
        int s2 = perm[e + 2];
        int s3 = perm[e + 3];
        uint v0 = xb[(size_t)s0 * 64 + lane];
        uint v1 = xb[(size_t)s1 * 64 + lane];
        uint v2 = xb[(size_t)s2 * 64 + lane];
        uint v3 = xb[(size_t)s3 * 64 + lane];
        ax += __uint_as_float(v0 << 16); ay += __uint_as_float(v0 & 0xffff0000u);
        ax += __uint_as_float(v1 << 16); ay += __uint_as_float(v1 & 0xffff0000u);
        ax += __uint_as_float(v2 << 16); ay += __uint_as_float(v2 & 0xffff0000u);
        ax += __uint_as_float(v3 << 16); ay += __uint_as_float(v3 & 0xffff0000u);
    }
    for (; e < end; ++e) {
        uint vv = xb[(size_t)perm[e] * 64 + lane];
        ax += __uint_as_float(vv << 16); ay += __uint_as_float(vv & 0xffff0000u);
    }
    if (BN) {
        int f0 = lane * 2;
        float deg1 = (float)(end - beg + 1);
        ax = ax * ss[f0]     + deg1 * ss[128 + f0];
        ay = ay * ss[f0 + 1] + deg1 * ss[128 + f0 + 1];
    }
    out[(size_t)node * 64 + lane] = ((uint)f2b(ay) << 16) | (uint)f2b(ax);
}

// ---------------- MFMA matmul: C[M x 128] = relu(A @ W + b), bf16 in, bf16 out ----------------
__global__ __launch_bounds__(256) void mfma_mm_kernel(const ushort* __restrict__ A,
                                                      const ushort* __restrict__ Wt, // Wt[n][k]
                                                      const float* __restrict__ b,
                                                      ushort* __restrict__ C, int M) {
    const int wid = threadIdx.x >> 6;
    const int lane = threadIdx.x & 63;
    const int row0 = blockIdx.x * 64 + wid * 16;
    const int r = lane & 15;
    const int kg = lane >> 4;

    const int arow = min(row0 + r, M - 1);
    const ushort* Arow = A + (size_t)arow * 128 + kg * 8;
    short8 a[4];
    #pragma unroll
    for (int kb = 0; kb < 4; ++kb)
        a[kb] = *(const short8*)(Arow + kb * 32);

    #pragma unroll
    for (int c = 0; c < 8; ++c) {
        f32x4 acc = {0.f, 0.f, 0.f, 0.f};
        const ushort* Wcol = Wt + (size_t)(c * 16 + r) * 128 + kg * 8;
        #pragma unroll
        for (int kb = 0; kb < 4; ++kb) {
            short8 bb = *(const short8*)(Wcol + kb * 32);
            acc = __builtin_amdgcn_mfma_f32_16x16x32_bf16(a[kb], bb, acc, 0, 0, 0);
        }
        float bias = b[c * 16 + r];
        #pragma unroll
        for (int j = 0; j < 4; ++j) {
            int orow = row0 + kg * 4 + j;
            if (orow < M) {
                float v = fmaxf(acc[j] + bias, 0.f);
                C[(size_t)orow * 128 + c * 16 + r] = f2b(v);
            }
        }
    }
}

// ---------------- fused: C[M x 2] = relu(A @ W(128x2) + b); col sums/sumsqs -> stats ----------------
__global__ __launch_bounds__(256) void mm2out_stats_kernel(const ushort* __restrict__ A,
                                                           const float* __restrict__ W,
                                                           const float* __restrict__ b,
                                                           float* __restrict__ C,
                                                           float* __restrict__ stats, int M) {
    __shared__ float Ws[256];
    __shared__ float4 red[256];
    const int tid = threadIdx.x;
    Ws[tid] = W[tid];
    __syncthreads();
    const int row = blockIdx.x * 256 + tid;
    float s0 = 0.f, s1 = 0.f;
    if (row < M) {
        const short8* a8 = (const short8*)(A + (size_t)row * 128);
        s0 = b[0]; s1 = b[1];
        #pragma unroll
        for (int k8 = 0; k8 < 16; ++k8) {
            short8 v = a8[k8];
            #pragma unroll
            for (int j = 0; j < 8; ++j) {
                float f = b2f((ushort)v[j]);
                int k = k8 * 8 + j;
                s0 += f * Ws[k * 2];
                s1 += f * Ws[k * 2 + 1];
            }
        }
        s0 = fmaxf(s0, 0.f); s1 = fmaxf(s1, 0.f);
        C[(size_t)row * 2 + 0] = s0;
        C[(size_t)row * 2 + 1] = s1;
    }
    red[tid] = make_float4(s0, s1, s0 * s0, s1 * s1);
    __syncthreads();
    for (int s = 128; s > 0; s >>= 1) {
        if (tid < s) {
            red[tid].x += red[tid + s].x;
            red[tid].y += red[tid + s].y;
            red[tid].z += red[tid + s].z;
            red[tid].w += red[tid + s].w;
        }
        __syncthreads();
    }
    if (tid == 0) {
        atomicAdd(&stats[0], red[0].x);
        atomicAdd(&stats[1], red[0].y);
        atomicAdd(&stats[2], red[0].z);
        atomicAdd(&stats[3], red[0].w);
    }
}

// ---------------- BN stats over 128 cols (bf16 input) ----------------
__global__ __launch_bounds__(256) void stats128_kernel(const ushort* __restrict__ h, int M,
                                                       float* __restrict__ stats) {
    __shared__ float ssum[256];
    __shared__ float ssq[256];
    const int tid = threadIdx.x;
    const int col = tid & 127;
    float sum = 0.f, sq = 0.f;
    for (int row = blockIdx.x * 2 + (tid >> 7); row < M; row += gridDim.x * 2) {
        float v = b2f(h[(size_t)row * 128 + col]);
        sum += v; sq += v * v;
    }
    ssum[tid] = sum; ssq[tid] = sq;
    __syncthreads();
    if (tid < 128) { ssum[tid] += ssum[tid + 128]; ssq[tid] += ssq[tid + 128]; }
    __syncthreads();
    if (tid < 128) {
        atomicAdd(&stats[tid], ssum[tid]);
        atomicAdd(&stats[128 + tid], ssq[tid]);
    }
}

__global__ __launch_bounds__(256) void bn_finalize128_kernel(float* __restrict__ ss,
                                                             const float* __restrict__ g,
                                                             const float* __restrict__ be,
                                                             float invM) {
    int c = threadIdx.x;
    if (c < 128) {
        float mean = ss[c] * invM;
        float var = ss[128 + c] * invM - mean * mean;
        float sc = rsqrtf(var + BN_EPS) * g[c];
        ss[c] = sc;
        ss[128 + c] = be[c] - mean * sc;
    }
}

// ---------------- final: finalize(2-col stats) + apply, f32 out ----------------
__global__ __launch_bounds__(256) void bn_apply2_kernel(const float* __restrict__ h,
                                                        const float* __restrict__ stats,
                                                        const float* __restrict__ g,
                                                        const float* __restrict__ be,
                                                        float* __restrict__ y, int n4, float invM) {
    float m0 = stats[0] * invM, m1 = stats[1] * invM;
    float v0 = stats[2] * invM - m0 * m0, v1 = stats[3] * invM - m1 * m1;
    float sc0 = rsqrtf(v0 + BN_EPS) * g[0], sc1 = rsqrtf(v1 + BN_EPS) * g[1];
    float sh0 = be[0] - m0 * sc0, sh1 = be[1] - m1 * sc1;
    int gid = blockIdx.x * 256 + threadIdx.x;
    if (gid >= n4) return;
    float4 v = ((const float4*)h)[gid];
    float4 o;
    o.x = v.x * sc0 + sh0;
    o.y = v.y * sc1 + sh1;
    o.z = v.z * sc0 + sh0;
    o.w = v.w * sc1 + sh1;
    ((float4*)y)[gid] = o;
}

extern "C" void kernel_launch(void* const* d_in, const int* in_sizes, int n_in,
                              void* d_out, int out_size, void* d_ws, size_t ws_size,
                              hipStream_t stream) {
    const float* x   = (const float*)d_in[0];
    const int*   ei  = (const int*)d_in[1];
    const float* w11 = (const float*)d_in[2];
    const float* b11 = (const float*)d_in[3];
    const float* w12 = (const float*)d_in[4];
    const float* b12 = (const float*)d_in[5];
    const float* g1  = (const float*)d_in[6];
    const float* be1 = (const float*)d_in[7];
    const float* w21 = (const float*)d_in[8];
    const float* b21 = (const float*)d_in[9];
    const float* w22 = (const float*)d_in[10];
    const float* b22 = (const float*)d_in[11];
    const float* g2  = (const float*)d_in[12];
    const float* be2 = (const float*)d_in[13];

    const int M  = N_NODES;
    const int nE = in_sizes[1] / 2;
    const int* src = ei;
    const int* dst = ei + nE;

    const size_t RB = (size_t)50048 * 128 * 2;      // padded bf16 feature buffer bytes
    char* p = (char*)d_ws;
    ushort* xb   = (ushort*)p;  p += RB;
    ushort* gbuf = (ushort*)p;  p += RB;
    ushort* tbuf = (ushort*)p;  p += RB;
    ushort* hbuf = (ushort*)p;  p += RB;
    float*  h2   = (float*)p;   p += 400128;        // 50000*2 f32
    ushort* wt11 = (ushort*)p;  p += 32768;
    ushort* wt12 = (ushort*)p;  p += 32768;
    ushort* wt21 = (ushort*)p;  p += 32768;
    int*    cnt  = (int*)p;     p += 3136 * 4;      // NBUCK*8 = 3128, padded
    float* stats1= (float*)p;   p += 256 * 4;
    float* stats2= (float*)p;   p += 16 * 4;
    int*    base = (int*)p;     p += 400 * 4;
    int*  rowptr = (int*)p;     p += (size_t)(M + 8) * 4;
    ushort* perm = (ushort*)p;  p += (size_t)nE * 2 + 64;
    uint*  bdata = (uint*)p;                         // NBUCK*8*SUBCAP*4 = 9.6 MB

    const float invM = 1.0f / (float)M;

    // ---- CSR build + converts ----
    zero4_kernel<<<4, 256, 0, stream>>>((float4*)cnt, 852);   // cnt + stats1 + stats2
    convert_x_kernel<<<(M * 32 + 255) / 256, 256, 0, stream>>>((const float4*)x, (ushort4*)xb, M * 32);
    convert_w_kernel<<<dim3(64, 3), 256, 0, stream>>>(w11, w12, w21, wt11, wt12, wt21);
    bucket_pass_kernel<<<1024, 256, 0, stream>>>(src, dst, nE, cnt, bdata);
    bucket_scan_kernel<<<1, 512, 0, stream>>>(cnt, base, rowptr + M);
    csr_build_kernel<<<NBUCK, 256, 0, stream>>>(cnt, base, bdata, rowptr, perm, M);

    // ---- layer 1 ----
    gather_kernel<false><<<(M + 3) / 4, 256, 0, stream>>>((const uint*)xb, rowptr, perm, nullptr, (uint*)gbuf, M);
    mfma_mm_kernel<<<(M + 63) / 64, 256, 0, stream>>>(gbuf, wt11, b11, tbuf, M);
    mfma_mm_kernel<<<(M + 63) / 64, 256, 0, stream>>>(tbuf, wt12, b12, hbuf, M);
    stats128_kernel<<<512, 256, 0, stream>>>(hbuf, M, stats1);
    bn_finalize128_kernel<<<1, 256, 0, stream>>>(stats1, g1, be1, invM);

    // ---- layer 2 (BN1 folded into gather) ----
    gather_kernel<true><<<(M + 3) / 4, 256, 0, stream>>>((const uint*)hbuf, rowptr, perm, stats1, (uint*)gbuf, M);
    mfma_mm_kernel<<<(M + 63) / 64, 256, 0, stream>>>(gbuf, wt21, b21, tbuf, M);
    mm2out_stats_kernel<<<(M + 255) / 256, 256, 0, stream>>>(tbuf, w22, b22, h2, stats2, M);
    bn_apply2_kernel<<<(M / 2 + 255) / 256, 256, 0, stream>>>(h2, stats2, g2, be2, (float*)d_out, M / 2, invM);
}

// Round 5
// 275.523 us; speedup vs baseline: 20.0670x; 1.4751x over previous
//
#include <hip/hip_runtime.h>

#define N_NODES 50000
#define BN_EPS 1e-5f
#define NBUCK 391
#define NCHUNK 1000
#define ENTCAP 5120

using short8 = __attribute__((ext_vector_type(8))) short;
using f32x4  = __attribute__((ext_vector_type(4))) float;

__device__ __forceinline__ float b2f(ushort h) { return __uint_as_float(((uint)h) << 16); }
__device__ __forceinline__ ushort f2b(float f) {
    uint u = __float_as_uint(f);
    u += 0x7FFF + ((u >> 16) & 1);   // round-to-nearest-even
    return (ushort)(u >> 16);
}
__device__ __forceinline__ int xcd_chunk(int bid) {
    return (bid & 7) * (NCHUNK / 8) + (bid >> 3);
}

// ---------------- zero ----------------
__global__ __launch_bounds__(256) void zero4_kernel(float4* __restrict__ p, int n4) {
    int i = blockIdx.x * 256 + threadIdx.x;
    if (i < n4) p[i] = make_float4(0.f, 0.f, 0.f, 0.f);
}

// ---------------- converts ----------------
__global__ __launch_bounds__(256) void convert_x_kernel(const float4* __restrict__ x4,
                                                        ushort4* __restrict__ xb, int n4) {
    int i = blockIdx.x * 256 + threadIdx.x;
    if (i < n4) {
        float4 v = x4[i];
        ushort4 o;
        o.x = f2b(v.x); o.y = f2b(v.y); o.z = f2b(v.z); o.w = f2b(v.w);
        xb[i] = o;
    }
}

// transpose+convert three 128x128 weights: Wt[n][k] = W[k][n]
__global__ __launch_bounds__(256) void convert_w_kernel(const float* __restrict__ w0,
                                                        const float* __restrict__ w1,
                                                        const float* __restrict__ w2,
                                                        ushort* __restrict__ o0,
                                                        ushort* __restrict__ o1,
                                                        ushort* __restrict__ o2) {
    const float* W = (blockIdx.y == 0) ? w0 : (blockIdx.y == 1) ? w1 : w2;
    ushort* O = (blockIdx.y == 0) ? o0 : (blockIdx.y == 1) ? o1 : o2;
    int id = blockIdx.x * 256 + threadIdx.x;   // 0..16383
    int k = id >> 7, n = id & 127;
    O[n * 128 + k] = f2b(W[id]);
}

// ---------------- radix pass 1: per-chunk LDS histogram ----------------
__global__ __launch_bounds__(256) void hist_pass_kernel(const int* __restrict__ dst, int nE,
                                                        int chunk, int* __restrict__ histT) {
    __shared__ int h[NBUCK];
    for (int i = threadIdx.x; i < NBUCK; i += 256) h[i] = 0;
    __syncthreads();
    const int c = xcd_chunk(blockIdx.x);
    const int lo = c * chunk, hi = min(lo + chunk, nE);
    for (int i = lo + threadIdx.x; i < hi; i += 256) atomicAdd(&h[dst[i] >> 7], 1);
    __syncthreads();
    for (int b = threadIdx.x; b < NBUCK; b += 256) histT[b * NCHUNK + c] = h[b];
}

// ---------------- radix: per-bucket totals ----------------
__global__ __launch_bounds__(256) void tot_kernel(const int* __restrict__ histT,
                                                  int* __restrict__ tot) {
    __shared__ int s[256];
    int acc = 0;
    for (int i = threadIdx.x; i < NCHUNK; i += 256) acc += histT[blockIdx.x * NCHUNK + i];
    s[threadIdx.x] = acc;
    __syncthreads();
    for (int d = 128; d > 0; d >>= 1) {
        if (threadIdx.x < d) s[threadIdx.x] += s[threadIdx.x + d];
        __syncthreads();
    }
    if (threadIdx.x == 0) tot[blockIdx.x] = s[0];
}

// ---------------- radix: per-bucket base + per-chunk exclusive offsets ----------------
__global__ __launch_bounds__(1024) void base_scan_kernel(const int* __restrict__ tot,
                                                         const int* __restrict__ histT,
                                                         int* __restrict__ base_bc,
                                                         int* __restrict__ bucketbase,
                                                         int* __restrict__ rowptr, int nE) {
    __shared__ int s[1024];
    const int b = blockIdx.x;
    const int t = threadIdx.x;
    // bucket base = sum of tot[0..b)
    int acc = 0;
    for (int i = t; i < b; i += 1024) acc += tot[i];
    s[t] = acc;
    __syncthreads();
    for (int d = 512; d > 0; d >>= 1) {
        if (t < d) s[t] += s[t + d];
        __syncthreads();
    }
    const int bbase = s[0];
    __syncthreads();
    // inclusive scan of this bucket's chunk counts
    int v = (t < NCHUNK) ? histT[b * NCHUNK + t] : 0;
    s[t] = v;
    __syncthreads();
    for (int d = 1; d < 1024; d <<= 1) {
        int u = (t >= d) ? s[t - d] : 0;
        __syncthreads();
        s[t] += u;
        __syncthreads();
    }
    if (t < NCHUNK) base_bc[b * NCHUNK + t] = bbase + s[t] - v;  // exclusive
    if (t == 0) {
        bucketbase[b] = bbase;
        if (b == NBUCK - 1) bucketbase[NBUCK] = bbase + tot[b];
        if (b == 0) rowptr[N_NODES] = nE;
    }
}

// ---------------- radix pass 2: placement ----------------
__global__ __launch_bounds__(256) void place_kernel(const int* __restrict__ src,
                                                    const int* __restrict__ dst, int nE,
                                                    int chunk,
                                                    const int* __restrict__ base_bc,
                                                    uint* __restrict__ bdata) {
    __shared__ int off[NBUCK];
    const int c = xcd_chunk(blockIdx.x);
    for (int i = threadIdx.x; i < NBUCK; i += 256) off[i] = base_bc[i * NCHUNK + c];
    __syncthreads();
    const int lo = c * chunk, hi = min(lo + chunk, nE);
    for (int i = lo + threadIdx.x; i < hi; i += 256) {
        int s = src[i], d = dst[i];
        int pos = atomicAdd(&off[d >> 7], 1);
        bdata[pos] = ((uint)(d & 127) << 16) | (uint)s;
    }
}

// ---------------- per-bucket LDS counting sort -> rowptr + perm ----------------
__global__ __launch_bounds__(256) void csr_build_kernel(const int* __restrict__ bucketbase,
                                                        const uint* __restrict__ bdata,
                                                        int* __restrict__ rowptr,
                                                        ushort* __restrict__ perm, int M) {
    __shared__ uint ent[ENTCAP];
    __shared__ int hist[128];
    __shared__ int scn[128];
    __shared__ int cur[128];
    const int b = blockIdx.x;
    const int tid = threadIdx.x;
    const int bb = bucketbase[b];
    const int nb = min(bucketbase[b + 1] - bb, ENTCAP);
    if (tid < 128) hist[tid] = 0;
    for (int i = tid; i < nb; i += 256) ent[i] = bdata[bb + i];
    __syncthreads();
    for (int i = tid; i < nb; i += 256) atomicAdd(&hist[ent[i] >> 16], 1);
    __syncthreads();
    if (tid < 128) scn[tid] = hist[tid];
    __syncthreads();
    for (int d = 1; d < 128; d <<= 1) {
        int v = 0;
        if (tid < 128 && tid >= d) v = scn[tid - d];
        __syncthreads();
        if (tid < 128) scn[tid] += v;
        __syncthreads();
    }
    if (tid < 128) {
        int ex = scn[tid] - hist[tid];   // exclusive scan
        cur[tid] = ex;
        int node = b * 128 + tid;
        if (node < M) rowptr[node] = bb + ex;
    }
    __syncthreads();
    for (int i = tid; i < nb; i += 256) {
        uint e = ent[i];
        int lp = atomicAdd(&cur[e >> 16], 1);
        perm[bb + lp] = (ushort)(e & 0xffffu);
    }
}

// ---------------- gather-aggregate (bf16), optional fused BN-apply of the input ----------------
// BN fold: sum_s BN(h[s]) + BN(h[n]) = (h[n]+sum h[s])*sc + (deg+1)*sh
template<bool BN>
__global__ __launch_bounds__(256) void gather_kernel(const uint* __restrict__ xb,
                                                     const int* __restrict__ rowptr,
                                                     const ushort* __restrict__ perm,
                                                     const float* __restrict__ ss,
                                                     uint* __restrict__ out, int M) {
    const int node = blockIdx.x * 4 + (threadIdx.x >> 6);
    if (node >= M) return;
    const int lane = threadIdx.x & 63;
    uint v = xb[(size_t)node * 64 + lane];
    float ax = __uint_as_float(v << 16);
    float ay = __uint_as_float(v & 0xffff0000u);
    const int beg = rowptr[node], end = rowptr[node + 1];
    int e = beg;
    for (; e + 4 <= end; e += 4) {
        int s0 = perm[e + 0];
        int s1 = perm[e + 1];
        int s2 = perm[e + 2];
        int s3 = perm[e + 3];
        uint v0 = xb[(size_t)s0 * 64 + lane];
        uint v1 = xb[(size_t)s1 * 64 + lane];
        uint v2 = xb[(size_t)s2 * 64 + lane];
        uint v3 = xb[(size_t)s3 * 64 + lane];
        ax += __uint_as_float(v0 << 16); ay += __uint_as_float(v0 & 0xffff0000u);
        ax += __uint_as_float(v1 << 16); ay += __uint_as_float(v1 & 0xffff0000u);
        ax += __uint_as_float(v2 << 16); ay += __uint_as_float(v2 & 0xffff0000u);
        ax += __uint_as_float(v3 << 16); ay += __uint_as_float(v3 & 0xffff0000u);
    }
    for (; e < end; ++e) {
        uint vv = xb[(size_t)perm[e] * 64 + lane];
        ax += __uint_as_float(vv << 16); ay += __uint_as_float(vv & 0xffff0000u);
    }
    if (BN) {
        int f0 = lane * 2;
        float deg1 = (float)(end - beg + 1);
        ax = ax * ss[f0]     + deg1 * ss[128 + f0];
        ay = ay * ss[f0 + 1] + deg1 * ss[128 + f0 + 1];
    }
    out[(size_t)node * 64 + lane] = ((uint)f2b(ay) << 16) | (uint)f2b(ax);
}

// ---------------- MFMA matmul: C[M x 128] = relu(A @ W + b), bf16 in, bf16 out ----------------
__global__ __launch_bounds__(256) void mfma_mm_kernel(const ushort* __restrict__ A,
                                                      const ushort* __restrict__ Wt, // Wt[n][k]
                                                      const float* __restrict__ b,
                                                      ushort* __restrict__ C, int M) {
    const int wid = threadIdx.x >> 6;
    const int lane = threadIdx.x & 63;
    const int row0 = blockIdx.x * 64 + wid * 16;
    const int r = lane & 15;
    const int kg = lane >> 4;

    const int arow = min(row0 + r, M - 1);
    const ushort* Arow = A + (size_t)arow * 128 + kg * 8;
    short8 a[4];
    #pragma unroll
    for (int kb = 0; kb < 4; ++kb)
        a[kb] = *(const short8*)(Arow + kb * 32);

    #pragma unroll
    for (int c = 0; c < 8; ++c) {
        f32x4 acc = {0.f, 0.f, 0.f, 0.f};
        const ushort* Wcol = Wt + (size_t)(c * 16 + r) * 128 + kg * 8;
        #pragma unroll
        for (int kb = 0; kb < 4; ++kb) {
            short8 bb = *(const short8*)(Wcol + kb * 32);
            acc = __builtin_amdgcn_mfma_f32_16x16x32_bf16(a[kb], bb, acc, 0, 0, 0);
        }
        float bias = b[c * 16 + r];
        #pragma unroll
        for (int j = 0; j < 4; ++j) {
            int orow = row0 + kg * 4 + j;
            if (orow < M) {
                float v = fmaxf(acc[j] + bias, 0.f);
                C[(size_t)orow * 128 + c * 16 + r] = f2b(v);
            }
        }
    }
}

// ---------------- fused: C[M x 2] = relu(A @ W(128x2) + b); col sums/sumsqs -> stats ----------------
__global__ __launch_bounds__(256) void mm2out_stats_kernel(const ushort* __restrict__ A,
                                                           const float* __restrict__ W,
                                                           const float* __restrict__ b,
                                                           float* __restrict__ C,
                                                           float* __restrict__ stats, int M) {
    __shared__ float Ws[256];
    __shared__ float4 red[256];
    const int tid = threadIdx.x;
    Ws[tid] = W[tid];
    __syncthreads();
    const int row = blockIdx.x * 256 + tid;
    float s0 = 0.f, s1 = 0.f;
    if (row < M) {
        const short8* a8 = (const short8*)(A + (size_t)row * 128);
        s0 = b[0]; s1 = b[1];
        #pragma unroll
        for (int k8 = 0; k8 < 16; ++k8) {
            short8 v = a8[k8];
            #pragma unroll
            for (int j = 0; j < 8; ++j) {
                float f = b2f((ushort)v[j]);
                int k = k8 * 8 + j;
                s0 += f * Ws[k * 2];
                s1 += f * Ws[k * 2 + 1];
            }
        }
        s0 = fmaxf(s0, 0.f); s1 = fmaxf(s1, 0.f);
        C[(size_t)row * 2 + 0] = s0;
        C[(size_t)row * 2 + 1] = s1;
    }
    red[tid] = make_float4(s0, s1, s0 * s0, s1 * s1);
    __syncthreads();
    for (int s = 128; s > 0; s >>= 1) {
        if (tid < s) {
            red[tid].x += red[tid + s].x;
            red[tid].y += red[tid + s].y;
            red[tid].z += red[tid + s].z;
            red[tid].w += red[tid + s].w;
        }
        __syncthreads();
    }
    if (tid == 0) {
        atomicAdd(&stats[0], red[0].x);
        atomicAdd(&stats[1], red[0].y);
        atomicAdd(&stats[2], red[0].z);
        atomicAdd(&stats[3], red[0].w);
    }
}

// ---------------- BN stats over 128 cols (bf16 input) ----------------
__global__ __launch_bounds__(256) void stats128_kernel(const ushort* __restrict__ h, int M,
                                                       float* __restrict__ stats) {
    __shared__ float ssum[256];
    __shared__ float ssq[256];
    const int tid = threadIdx.x;
    const int col = tid & 127;
    float sum = 0.f, sq = 0.f;
    for (int row = blockIdx.x * 2 + (tid >> 7); row < M; row += gridDim.x * 2) {
        float v = b2f(h[(size_t)row * 128 + col]);
        sum += v; sq += v * v;
    }
    ssum[tid] = sum; ssq[tid] = sq;
    __syncthreads();
    if (tid < 128) { ssum[tid] += ssum[tid + 128]; ssq[tid] += ssq[tid + 128]; }
    __syncthreads();
    if (tid < 128) {
        atomicAdd(&stats[tid], ssum[tid]);
        atomicAdd(&stats[128 + tid], ssq[tid]);
    }
}

__global__ __launch_bounds__(256) void bn_finalize128_kernel(float* __restrict__ ss,
                                                             const float* __restrict__ g,
                                                             const float* __restrict__ be,
                                                             float invM) {
    int c = threadIdx.x;
    if (c < 128) {
        float mean = ss[c] * invM;
        float var = ss[128 + c] * invM - mean * mean;
        float sc = rsqrtf(var + BN_EPS) * g[c];
        ss[c] = sc;
        ss[128 + c] = be[c] - mean * sc;
    }
}

// ---------------- final: finalize(2-col stats) + apply, f32 out ----------------
__global__ __launch_bounds__(256) void bn_apply2_kernel(const float* __restrict__ h,
                                                        const float* __restrict__ stats,
                                                        const float* __restrict__ g,
                                                        const float* __restrict__ be,
                                                        float* __restrict__ y, int n4, float invM) {
    float m0 = stats[0] * invM, m1 = stats[1] * invM;
    float v0 = stats[2] * invM - m0 * m0, v1 = stats[3] * invM - m1 * m1;
    float sc0 = rsqrtf(v0 + BN_EPS) * g[0], sc1 = rsqrtf(v1 + BN_EPS) * g[1];
    float sh0 = be[0] - m0 * sc0, sh1 = be[1] - m1 * sc1;
    int gid = blockIdx.x * 256 + threadIdx.x;
    if (gid >= n4) return;
    float4 v = ((const float4*)h)[gid];
    float4 o;
    o.x = v.x * sc0 + sh0;
    o.y = v.y * sc1 + sh1;
    o.z = v.z * sc0 + sh0;
    o.w = v.w * sc1 + sh1;
    ((float4*)y)[gid] = o;
}

extern "C" void kernel_launch(void* const* d_in, const int* in_sizes, int n_in,
                              void* d_out, int out_size, void* d_ws, size_t ws_size,
                              hipStream_t stream) {
    const float* x   = (const float*)d_in[0];
    const int*   ei  = (const int*)d_in[1];
    const float* w11 = (const float*)d_in[2];
    const float* b11 = (const float*)d_in[3];
    const float* w12 = (const float*)d_in[4];
    const float* b12 = (const float*)d_in[5];
    const float* g1  = (const float*)d_in[6];
    const float* be1 = (const float*)d_in[7];
    const float* w21 = (const float*)d_in[8];
    const float* b21 = (const float*)d_in[9];
    const float* w22 = (const float*)d_in[10];
    const float* b22 = (const float*)d_in[11];
    const float* g2  = (const float*)d_in[12];
    const float* be2 = (const float*)d_in[13];

    const int M  = N_NODES;
    const int nE = in_sizes[1] / 2;
    const int* src = ei;
    const int* dst = ei + nE;
    const int chunk = (nE + NCHUNK - 1) / NCHUNK;

    const size_t RB = (size_t)50048 * 128 * 2;      // padded bf16 feature buffer bytes
    char* p = (char*)d_ws;
    ushort* xb   = (ushort*)p;  p += RB;
    ushort* gbuf = (ushort*)p;  p += RB;
    ushort* tbuf = (ushort*)p;  p += RB;
    ushort* hbuf = (ushort*)p;  p += RB;
    float*  h2   = (float*)p;   p += 400128;        // 50000*2 f32
    ushort* wt11 = (ushort*)p;  p += 32768;
    ushort* wt12 = (ushort*)p;  p += 32768;
    ushort* wt21 = (ushort*)p;  p += 32768;
    float* stats1= (float*)p;   p += 256 * 4;
    float* stats2= (float*)p;   p += 16 * 4;
    int*  histT  = (int*)p;     p += (size_t)NBUCK * NCHUNK * 4;   // 1.56 MB
    int*  base_bc= (int*)p;     p += (size_t)NBUCK * NCHUNK * 4;   // 1.56 MB
    int*  tot    = (int*)p;     p += 512 * 4;
    int*  bktbase= (int*)p;     p += 512 * 4;
    int*  rowptr = (int*)p;     p += (size_t)(M + 8) * 4;
    ushort* perm = (ushort*)p;  p += (size_t)nE * 2 + 64;
    uint*  bdata = (uint*)p;                         // nE*4 = 6.4 MB

    const float invM = 1.0f / (float)M;

    // ---- converts + CSR build (deterministic radix) ----
    zero4_kernel<<<1, 256, 0, stream>>>((float4*)stats1, 68);   // stats1(256)+stats2(16)
    convert_x_kernel<<<(M * 32 + 255) / 256, 256, 0, stream>>>((const float4*)x, (ushort4*)xb, M * 32);
    convert_w_kernel<<<dim3(64, 3), 256, 0, stream>>>(w11, w12, w21, wt11, wt12, wt21);
    hist_pass_kernel<<<NCHUNK, 256, 0, stream>>>(dst, nE, chunk, histT);
    tot_kernel<<<NBUCK, 256, 0, stream>>>(histT, tot);
    base_scan_kernel<<<NBUCK, 1024, 0, stream>>>(tot, histT, base_bc, bktbase, rowptr, nE);
    place_kernel<<<NCHUNK, 256, 0, stream>>>(src, dst, nE, chunk, base_bc, bdata);
    csr_build_kernel<<<NBUCK, 256, 0, stream>>>(bktbase, bdata, rowptr, perm, M);

    // ---- layer 1 ----
    gather_kernel<false><<<(M + 3) / 4, 256, 0, stream>>>((const uint*)xb, rowptr, perm, nullptr, (uint*)gbuf, M);
    mfma_mm_kernel<<<(M + 63) / 64, 256, 0, stream>>>(gbuf, wt11, b11, tbuf, M);
    mfma_mm_kernel<<<(M + 63) / 64, 256, 0, stream>>>(tbuf, wt12, b12, hbuf, M);
    stats128_kernel<<<512, 256, 0, stream>>>(hbuf, M, stats1);
    bn_finalize128_kernel<<<1, 256, 0, stream>>>(stats1, g1, be1, invM);

    // ---- layer 2 (BN1 folded into gather) ----
    gather_kernel<true><<<(M + 3) / 4, 256, 0, stream>>>((const uint*)hbuf, rowptr, perm, stats1, (uint*)gbuf, M);
    mfma_mm_kernel<<<(M + 63) / 64, 256, 0, stream>>>(gbuf, wt21, b21, tbuf, M);
    mm2out_stats_kernel<<<(M + 255) / 256, 256, 0, stream>>>(tbuf, w22, b22, h2, stats2, M);
    bn_apply2_kernel<<<(M / 2 + 255) / 256, 256, 0, stream>>>(h2, stats2, g2, be2, (float*)d_out, M / 2, invM);
}

// Round 6
// 245.575 us; speedup vs baseline: 22.5142x; 1.1220x over previous
//
#include <hip/hip_runtime.h>

#define N_NODES 50000
#define BN_EPS 1e-5f
#define NBUCK 391
#define NCHUNK 1000
#define ENTCAP 5120

using short8 = __attribute__((ext_vector_type(8))) short;
using f32x4  = __attribute__((ext_vector_type(4))) float;

__device__ __forceinline__ float b2f(ushort h) { return __uint_as_float(((uint)h) << 16); }
__device__ __forceinline__ float blo(uint v) { return __uint_as_float(v << 16); }
__device__ __forceinline__ float bhi(uint v) { return __uint_as_float(v & 0xffff0000u); }
__device__ __forceinline__ ushort f2b(float f) {
    uint u = __float_as_uint(f);
    u += 0x7FFF + ((u >> 16) & 1);   // round-to-nearest-even
    return (ushort)(u >> 16);
}
__device__ __forceinline__ uint packb(float lo, float hi) {
    return ((uint)f2b(hi) << 16) | (uint)f2b(lo);
}
__device__ __forceinline__ int xcd_chunk(int bid) {
    return (bid & 7) * (NCHUNK / 8) + (bid >> 3);
}

// ---------------- zero ----------------
__global__ __launch_bounds__(256) void zero4_kernel(float4* __restrict__ p, int n4) {
    int i = blockIdx.x * 256 + threadIdx.x;
    if (i < n4) p[i] = make_float4(0.f, 0.f, 0.f, 0.f);
}

// ---------------- converts ----------------
__global__ __launch_bounds__(256) void convert_x_kernel(const float4* __restrict__ x4,
                                                        ushort4* __restrict__ xb, int n4) {
    int i = blockIdx.x * 256 + threadIdx.x;
    if (i < n4) {
        float4 v = x4[i];
        ushort4 o;
        o.x = f2b(v.x); o.y = f2b(v.y); o.z = f2b(v.z); o.w = f2b(v.w);
        xb[i] = o;
    }
}

// transpose+convert three 128x128 weights: Wt[n][k] = W[k][n]
__global__ __launch_bounds__(256) void convert_w_kernel(const float* __restrict__ w0,
                                                        const float* __restrict__ w1,
                                                        const float* __restrict__ w2,
                                                        ushort* __restrict__ o0,
                                                        ushort* __restrict__ o1,
                                                        ushort* __restrict__ o2) {
    const float* W = (blockIdx.y == 0) ? w0 : (blockIdx.y == 1) ? w1 : w2;
    ushort* O = (blockIdx.y == 0) ? o0 : (blockIdx.y == 1) ? o1 : o2;
    int id = blockIdx.x * 256 + threadIdx.x;   // 0..16383
    int k = id >> 7, n = id & 127;
    O[n * 128 + k] = f2b(W[id]);
}

// ---------------- radix pass 1: per-chunk LDS histogram ----------------
__global__ __launch_bounds__(256) void hist_pass_kernel(const int* __restrict__ dst, int nE,
                                                        int chunk, int* __restrict__ histT) {
    __shared__ int h[NBUCK];
    for (int i = threadIdx.x; i < NBUCK; i += 256) h[i] = 0;
    __syncthreads();
    const int c = xcd_chunk(blockIdx.x);
    const int lo = c * chunk, hi = min(lo + chunk, nE);
    for (int i = lo + threadIdx.x; i < hi; i += 256) atomicAdd(&h[dst[i] >> 7], 1);
    __syncthreads();
    for (int b = threadIdx.x; b < NBUCK; b += 256) histT[b * NCHUNK + c] = h[b];
}

// ---------------- radix: per-bucket totals ----------------
__global__ __launch_bounds__(256) void tot_kernel(const int* __restrict__ histT,
                                                  int* __restrict__ tot) {
    __shared__ int s[256];
    int acc = 0;
    for (int i = threadIdx.x; i < NCHUNK; i += 256) acc += histT[blockIdx.x * NCHUNK + i];
    s[threadIdx.x] = acc;
    __syncthreads();
    for (int d = 128; d > 0; d >>= 1) {
        if (threadIdx.x < d) s[threadIdx.x] += s[threadIdx.x + d];
        __syncthreads();
    }
    if (threadIdx.x == 0) tot[blockIdx.x] = s[0];
}

// ---------------- radix: per-bucket base + per-chunk exclusive offsets ----------------
__global__ __launch_bounds__(1024) void base_scan_kernel(const int* __restrict__ tot,
                                                         const int* __restrict__ histT,
                                                         int* __restrict__ base_bc,
                                                         int* __restrict__ bucketbase,
                                                         int* __restrict__ rowptr, int nE) {
    __shared__ int s[1024];
    const int b = blockIdx.x;
    const int t = threadIdx.x;
    // bucket base = sum of tot[0..b)
    int acc = 0;
    for (int i = t; i < b; i += 1024) acc += tot[i];
    s[t] = acc;
    __syncthreads();
    for (int d = 512; d > 0; d >>= 1) {
        if (t < d) s[t] += s[t + d];
        __syncthreads();
    }
    const int bbase = s[0];
    __syncthreads();
    // inclusive scan of this bucket's chunk counts
    int v = (t < NCHUNK) ? histT[b * NCHUNK + t] : 0;
    s[t] = v;
    __syncthreads();
    for (int d = 1; d < 1024; d <<= 1) {
        int u = (t >= d) ? s[t - d] : 0;
        __syncthreads();
        s[t] += u;
        __syncthreads();
    }
    if (t < NCHUNK) base_bc[b * NCHUNK + t] = bbase + s[t] - v;  // exclusive
    if (t == 0) {
        bucketbase[b] = bbase;
        if (b == NBUCK - 1) bucketbase[NBUCK] = bbase + tot[b];
        if (b == 0) rowptr[N_NODES] = nE;
    }
}

// ---------------- radix pass 2: placement ----------------
__global__ __launch_bounds__(256) void place_kernel(const int* __restrict__ src,
                                                    const int* __restrict__ dst, int nE,
                                                    int chunk,
                                                    const int* __restrict__ base_bc,
                                                    uint* __restrict__ bdata) {
    __shared__ int off[NBUCK];
    const int c = xcd_chunk(blockIdx.x);
    for (int i = threadIdx.x; i < NBUCK; i += 256) off[i] = base_bc[i * NCHUNK + c];
    __syncthreads();
    const int lo = c * chunk, hi = min(lo + chunk, nE);
    for (int i = lo + threadIdx.x; i < hi; i += 256) {
        int s = src[i], d = dst[i];
        int pos = atomicAdd(&off[d >> 7], 1);
        bdata[pos] = ((uint)(d & 127) << 16) | (uint)s;
    }
}

// ---------------- per-bucket LDS counting sort -> rowptr + perm ----------------
__global__ __launch_bounds__(256) void csr_build_kernel(const int* __restrict__ bucketbase,
                                                        const uint* __restrict__ bdata,
                                                        int* __restrict__ rowptr,
                                                        ushort* __restrict__ perm, int M) {
    __shared__ uint ent[ENTCAP];
    __shared__ int hist[128];
    __shared__ int scn[128];
    __shared__ int cur[128];
    const int b = blockIdx.x;
    const int tid = threadIdx.x;
    const int bb = bucketbase[b];
    const int nb = min(bucketbase[b + 1] - bb, ENTCAP);
    if (tid < 128) hist[tid] = 0;
    for (int i = tid; i < nb; i += 256) ent[i] = bdata[bb + i];
    __syncthreads();
    for (int i = tid; i < nb; i += 256) atomicAdd(&hist[ent[i] >> 16], 1);
    __syncthreads();
    if (tid < 128) scn[tid] = hist[tid];
    __syncthreads();
    for (int d = 1; d < 128; d <<= 1) {
        int v = 0;
        if (tid < 128 && tid >= d) v = scn[tid - d];
        __syncthreads();
        if (tid < 128) scn[tid] += v;
        __syncthreads();
    }
    if (tid < 128) {
        int ex = scn[tid] - hist[tid];   // exclusive scan
        cur[tid] = ex;
        int node = b * 128 + tid;
        if (node < M) rowptr[node] = bb + ex;
    }
    __syncthreads();
    for (int i = tid; i < nb; i += 256) {
        uint e = ent[i];
        int lp = atomicAdd(&cur[e >> 16], 1);
        perm[bb + lp] = (ushort)(e & 0xffffu);
    }
}

// ---------------- gather-aggregate (bf16), 16 lanes per edge (4 edges in parallel) ----------
// BN fold: sum_s BN(h[s]) + BN(h[n]) = (h[n]+sum h[s])*sc + (deg+1)*sh
template<bool BN>
__global__ __launch_bounds__(256) void gather_kernel(const uint4* __restrict__ xb,
                                                     const int* __restrict__ rowptr,
                                                     const ushort* __restrict__ perm,
                                                     const float* __restrict__ ss,
                                                     uint4* __restrict__ out, int M) {
    const int node = blockIdx.x * 4 + (threadIdx.x >> 6);
    if (node >= M) return;
    const int lane = threadIdx.x & 63;
    const int g = lane >> 4;        // edge slot 0..3
    const int r = lane & 15;        // 16B chunk within row (features r*8..r*8+7)
    float acc[8];
    if (g == 0) {
        uint4 v = xb[node * 16 + r];
        acc[0] = blo(v.x); acc[1] = bhi(v.x);
        acc[2] = blo(v.y); acc[3] = bhi(v.y);
        acc[4] = blo(v.z); acc[5] = bhi(v.z);
        acc[6] = blo(v.w); acc[7] = bhi(v.w);
    } else {
        #pragma unroll
        for (int k = 0; k < 8; ++k) acc[k] = 0.f;
    }
    const int beg = rowptr[node], end = rowptr[node + 1];
    int e = beg + g;
    while (e + 4 < end) {           // this group's edges: e and e+4
        int s0 = perm[e];
        int s1 = perm[e + 4];
        uint4 v0 = xb[s0 * 16 + r];
        uint4 v1 = xb[s1 * 16 + r];
        acc[0] += blo(v0.x); acc[1] += bhi(v0.x);
        acc[2] += blo(v0.y); acc[3] += bhi(v0.y);
        acc[4] += blo(v0.z); acc[5] += bhi(v0.z);
        acc[6] += blo(v0.w); acc[7] += bhi(v0.w);
        acc[0] += blo(v1.x); acc[1] += bhi(v1.x);
        acc[2] += blo(v1.y); acc[3] += bhi(v1.y);
        acc[4] += blo(v1.z); acc[5] += bhi(v1.z);
        acc[6] += blo(v1.w); acc[7] += bhi(v1.w);
        e += 8;
    }
    if (e < end) {
        uint4 v0 = xb[(int)perm[e] * 16 + r];
        acc[0] += blo(v0.x); acc[1] += bhi(v0.x);
        acc[2] += blo(v0.y); acc[3] += bhi(v0.y);
        acc[4] += blo(v0.z); acc[5] += bhi(v0.z);
        acc[6] += blo(v0.w); acc[7] += bhi(v0.w);
    }
    // reduce across the 4 edge-groups
    #pragma unroll
    for (int k = 0; k < 8; ++k) {
        acc[k] += __shfl_xor(acc[k], 16);
        acc[k] += __shfl_xor(acc[k], 32);
    }
    if (g == 0) {
        if (BN) {
            const int f0 = r * 8;
            const float deg1 = (float)(end - beg + 1);
            #pragma unroll
            for (int k = 0; k < 8; ++k)
                acc[k] = acc[k] * ss[f0 + k] + deg1 * ss[128 + f0 + k];
        }
        uint4 o;
        o.x = packb(acc[0], acc[1]);
        o.y = packb(acc[2], acc[3]);
        o.z = packb(acc[4], acc[5]);
        o.w = packb(acc[6], acc[7]);
        out[node * 16 + r] = o;
    }
}

// ---------------- MFMA matmul: C[M x 128] = relu(A @ W + b), bf16 in, bf16 out ----------------
__global__ __launch_bounds__(256) void mfma_mm_kernel(const ushort* __restrict__ A,
                                                      const ushort* __restrict__ Wt, // Wt[n][k]
                                                      const float* __restrict__ b,
                                                      ushort* __restrict__ C, int M) {
    const int wid = threadIdx.x >> 6;
    const int lane = threadIdx.x & 63;
    const int row0 = blockIdx.x * 64 + wid * 16;
    const int r = lane & 15;
    const int kg = lane >> 4;

    const int arow = min(row0 + r, M - 1);
    const ushort* Arow = A + (size_t)arow * 128 + kg * 8;
    short8 a[4];
    #pragma unroll
    for (int kb = 0; kb < 4; ++kb)
        a[kb] = *(const short8*)(Arow + kb * 32);

    #pragma unroll
    for (int c = 0; c < 8; ++c) {
        f32x4 acc = {0.f, 0.f, 0.f, 0.f};
        const ushort* Wcol = Wt + (size_t)(c * 16 + r) * 128 + kg * 8;
        #pragma unroll
        for (int kb = 0; kb < 4; ++kb) {
            short8 bb = *(const short8*)(Wcol + kb * 32);
            acc = __builtin_amdgcn_mfma_f32_16x16x32_bf16(a[kb], bb, acc, 0, 0, 0);
        }
        float bias = b[c * 16 + r];
        #pragma unroll
        for (int j = 0; j < 4; ++j) {
            int orow = row0 + kg * 4 + j;
            if (orow < M) {
                float v = fmaxf(acc[j] + bias, 0.f);
                C[(size_t)orow * 128 + c * 16 + r] = f2b(v);
            }
        }
    }
}

// ---------------- fused layer-2 tail: relu(A@W21+b21) @ W22 + b22 -> relu -> h2 + stats ----
__global__ __launch_bounds__(256) void mm2_fused_kernel(const ushort* __restrict__ A,
                                                        const ushort* __restrict__ Wt,  // W21t[n][k]
                                                        const float* __restrict__ b1,
                                                        const float* __restrict__ W22,  // [128][2]
                                                        const float* __restrict__ b22,
                                                        float* __restrict__ h2,
                                                        float* __restrict__ pblk, int M) {
    __shared__ float bred[4][4];
    const int wid = threadIdx.x >> 6;
    const int lane = threadIdx.x & 63;
    const int row0 = blockIdx.x * 64 + wid * 16;
    const int r = lane & 15;
    const int kg = lane >> 4;

    const int arow = min(row0 + r, M - 1);
    const ushort* Arow = A + (size_t)arow * 128 + kg * 8;
    short8 a[4];
    #pragma unroll
    for (int kb = 0; kb < 4; ++kb)
        a[kb] = *(const short8*)(Arow + kb * 32);

    float w2a[8], w2b[8];
    #pragma unroll
    for (int c = 0; c < 8; ++c) {
        w2a[c] = W22[(c * 16 + r) * 2 + 0];
        w2b[c] = W22[(c * 16 + r) * 2 + 1];
    }

    float s0[4] = {0.f, 0.f, 0.f, 0.f};
    float s1[4] = {0.f, 0.f, 0.f, 0.f};
    #pragma unroll
    for (int c = 0; c < 8; ++c) {
        f32x4 acc = {0.f, 0.f, 0.f, 0.f};
        const ushort* Wcol = Wt + (size_t)(c * 16 + r) * 128 + kg * 8;
        #pragma unroll
        for (int kb = 0; kb < 4; ++kb) {
            short8 bb = *(const short8*)(Wcol + kb * 32);
            acc = __builtin_amdgcn_mfma_f32_16x16x32_bf16(a[kb], bb, acc, 0, 0, 0);
        }
        float bias = b1[c * 16 + r];
        #pragma unroll
        for (int j = 0; j < 4; ++j) {
            int orow = row0 + kg * 4 + j;
            float v = fmaxf(acc[j] + bias, 0.f);
            if (orow >= M) v = 0.f;
            s0[j] += v * w2a[c];
            s1[j] += v * w2b[c];
        }
    }
    // reduce over r (16 lanes within a kg group)
    #pragma unroll
    for (int j = 0; j < 4; ++j) {
        #pragma unroll
        for (int d = 1; d < 16; d <<= 1) {
            s0[j] += __shfl_xor(s0[j], d);
            s1[j] += __shfl_xor(s1[j], d);
        }
    }
    float bs[4] = {0.f, 0.f, 0.f, 0.f};
    if (r == 0) {
        const float bb0 = b22[0], bb1 = b22[1];
        #pragma unroll
        for (int j = 0; j < 4; ++j) {
            int orow = row0 + kg * 4 + j;
            if (orow < M) {
                float o0 = fmaxf(s0[j] + bb0, 0.f);
                float o1 = fmaxf(s1[j] + bb1, 0.f);
                h2[(size_t)orow * 2 + 0] = o0;
                h2[(size_t)orow * 2 + 1] = o1;
                bs[0] += o0; bs[1] += o1; bs[2] += o0 * o0; bs[3] += o1 * o1;
            }
        }
    }
    #pragma unroll
    for (int k = 0; k < 4; ++k) {
        bs[k] += __shfl_xor(bs[k], 16);
        bs[k] += __shfl_xor(bs[k], 32);
    }
    if (lane == 0) {
        #pragma unroll
        for (int k = 0; k < 4; ++k) bred[wid][k] = bs[k];
    }
    __syncthreads();
    if (threadIdx.x < 4)
        pblk[(size_t)blockIdx.x * 4 + threadIdx.x] =
            bred[0][threadIdx.x] + bred[1][threadIdx.x] + bred[2][threadIdx.x] + bred[3][threadIdx.x];
}

// ---------------- BN stats over 128 cols (bf16 input) ----------------
__global__ __launch_bounds__(256) void stats128_kernel(const ushort* __restrict__ h, int M,
                                                       float* __restrict__ stats) {
    __shared__ float ssum[256];
    __shared__ float ssq[256];
    const int tid = threadIdx.x;
    const int col = tid & 127;
    float sum = 0.f, sq = 0.f;
    for (int row = blockIdx.x * 2 + (tid >> 7); row < M; row += gridDim.x * 2) {
        float v = b2f(h[(size_t)row * 128 + col]);
        sum += v; sq += v * v;
    }
    ssum[tid] = sum; ssq[tid] = sq;
    __syncthreads();
    if (tid < 128) { ssum[tid] += ssum[tid + 128]; ssq[tid] += ssq[tid + 128]; }
    __syncthreads();
    if (tid < 128) {
        atomicAdd(&stats[tid], ssum[tid]);
        atomicAdd(&stats[128 + tid], ssq[tid]);
    }
}

__global__ __launch_bounds__(256) void bn_finalize128_kernel(float* __restrict__ ss,
                                                             const float* __restrict__ g,
                                                             const float* __restrict__ be,
                                                             float invM) {
    int c = threadIdx.x;
    if (c < 128) {
        float mean = ss[c] * invM;
        float var = ss[128 + c] * invM - mean * mean;
        float sc = rsqrtf(var + BN_EPS) * g[c];
        ss[c] = sc;
        ss[128 + c] = be[c] - mean * sc;
    }
}

// ---------------- reduce pblk -> scale/shift for the 2-col BN ----------------
__global__ __launch_bounds__(256) void fin2_kernel(const float* __restrict__ pblk, int nblk,
                                                   const float* __restrict__ g,
                                                   const float* __restrict__ be,
                                                   float* __restrict__ stats, float invM) {
    __shared__ float red[256][4];
    const int tid = threadIdx.x;
    float s[4] = {0.f, 0.f, 0.f, 0.f};
    for (int b = tid; b < nblk; b += 256) {
        #pragma unroll
        for (int k = 0; k < 4; ++k) s[k] += pblk[(size_t)b * 4 + k];
    }
    #pragma unroll
    for (int k = 0; k < 4; ++k) red[tid][k] = s[k];
    __syncthreads();
    for (int d = 128; d > 0; d >>= 1) {
        if (tid < d) {
            #pragma unroll
            for (int k = 0; k < 4; ++k) red[tid][k] += red[tid + d][k];
        }
        __syncthreads();
    }
    if (tid == 0) {
        float m0 = red[0][0] * invM, m1 = red[0][1] * invM;
        float v0 = red[0][2] * invM - m0 * m0, v1 = red[0][3] * invM - m1 * m1;
        float sc0 = rsqrtf(v0 + BN_EPS) * g[0], sc1 = rsqrtf(v1 + BN_EPS) * g[1];
        stats[0] = sc0;
        stats[1] = sc1;
        stats[2] = be[0] - m0 * sc0;
        stats[3] = be[1] - m1 * sc1;
    }
}

// ---------------- final BN apply, f32 out ----------------
__global__ __launch_bounds__(256) void bn_apply2_kernel(const float* __restrict__ h,
                                                        const float* __restrict__ stats,
                                                        float* __restrict__ y, int n4) {
    float sc0 = stats[0], sc1 = stats[1], sh0 = stats[2], sh1 = stats[3];
    int gid = blockIdx.x * 256 + threadIdx.x;
    if (gid >= n4) return;
    float4 v = ((const float4*)h)[gid];
    float4 o;
    o.x = v.x * sc0 + sh0;
    o.y = v.y * sc1 + sh1;
    o.z = v.z * sc0 + sh0;
    o.w = v.w * sc1 + sh1;
    ((float4*)y)[gid] = o;
}

extern "C" void kernel_launch(void* const* d_in, const int* in_sizes, int n_in,
                              void* d_out, int out_size, void* d_ws, size_t ws_size,
                              hipStream_t stream) {
    const float* x   = (const float*)d_in[0];
    const int*   ei  = (const int*)d_in[1];
    const float* w11 = (const float*)d_in[2];
    const float* b11 = (const float*)d_in[3];
    const float* w12 = (const float*)d_in[4];
    const float* b12 = (const float*)d_in[5];
    const float* g1  = (const float*)d_in[6];
    const float* be1 = (const float*)d_in[7];
    const float* w21 = (const float*)d_in[8];
    const float* b21 = (const float*)d_in[9];
    const float* w22 = (const float*)d_in[10];
    const float* b22 = (const float*)d_in[11];
    const float* g2  = (const float*)d_in[12];
    const float* be2 = (const float*)d_in[13];

    const int M  = N_NODES;
    const int nE = in_sizes[1] / 2;
    const int* src = ei;
    const int* dst = ei + nE;
    const int chunk = (nE + NCHUNK - 1) / NCHUNK;
    const int nblk = (M + 63) / 64;

    const size_t RB = (size_t)50048 * 128 * 2;      // padded bf16 feature buffer bytes
    char* p = (char*)d_ws;
    ushort* xb   = (ushort*)p;  p += RB;
    ushort* gbuf = (ushort*)p;  p += RB;
    ushort* tbuf = (ushort*)p;  p += RB;
    ushort* hbuf = (ushort*)p;  p += RB;
    float*  h2   = (float*)p;   p += 400128;        // 50000*2 f32
    ushort* wt11 = (ushort*)p;  p += 32768;
    ushort* wt12 = (ushort*)p;  p += 32768;
    ushort* wt21 = (ushort*)p;  p += 32768;
    float* stats1= (float*)p;   p += 256 * 4;
    float* stats2= (float*)p;   p += 16 * 4;
    float* pblk  = (float*)p;   p += (size_t)nblk * 4 * 4 + 64;
    int*  histT  = (int*)p;     p += (size_t)NBUCK * NCHUNK * 4;   // 1.56 MB
    int*  base_bc= (int*)p;     p += (size_t)NBUCK * NCHUNK * 4;   // 1.56 MB
    int*  tot    = (int*)p;     p += 512 * 4;
    int*  bktbase= (int*)p;     p += 512 * 4;
    int*  rowptr = (int*)p;     p += (size_t)(M + 8) * 4;
    ushort* perm = (ushort*)p;  p += (size_t)nE * 2 + 64;
    uint*  bdata = (uint*)p;                         // nE*4 = 6.4 MB

    const float invM = 1.0f / (float)M;

    // ---- converts + CSR build (deterministic radix) ----
    zero4_kernel<<<1, 256, 0, stream>>>((float4*)stats1, 68);   // stats1(256)+stats2(16)
    convert_x_kernel<<<(M * 32 + 255) / 256, 256, 0, stream>>>((const float4*)x, (ushort4*)xb, M * 32);
    convert_w_kernel<<<dim3(64, 3), 256, 0, stream>>>(w11, w12, w21, wt11, wt12, wt21);
    hist_pass_kernel<<<NCHUNK, 256, 0, stream>>>(dst, nE, chunk, histT);
    tot_kernel<<<NBUCK, 256, 0, stream>>>(histT, tot);
    base_scan_kernel<<<NBUCK, 1024, 0, stream>>>(tot, histT, base_bc, bktbase, rowptr, nE);
    place_kernel<<<NCHUNK, 256, 0, stream>>>(src, dst, nE, chunk, base_bc, bdata);
    csr_build_kernel<<<NBUCK, 256, 0, stream>>>(bktbase, bdata, rowptr, perm, M);

    // ---- layer 1 ----
    gather_kernel<false><<<(M + 3) / 4, 256, 0, stream>>>((const uint4*)xb, rowptr, perm, nullptr, (uint4*)gbuf, M);
    mfma_mm_kernel<<<nblk, 256, 0, stream>>>(gbuf, wt11, b11, tbuf, M);
    mfma_mm_kernel<<<nblk, 256, 0, stream>>>(tbuf, wt12, b12, hbuf, M);
    stats128_kernel<<<512, 256, 0, stream>>>(hbuf, M, stats1);
    bn_finalize128_kernel<<<1, 256, 0, stream>>>(stats1, g1, be1, invM);

    // ---- layer 2 (BN1 folded into gather; 128->2 projection fused into GEMM) ----
    gather_kernel<true><<<(M + 3) / 4, 256, 0, stream>>>((const uint4*)hbuf, rowptr, perm, stats1, (uint4*)gbuf, M);
    mm2_fused_kernel<<<nblk, 256, 0, stream>>>(gbuf, wt21, b21, w22, b22, h2, pblk, M);
    fin2_kernel<<<1, 256, 0, stream>>>(pblk, nblk, g2, be2, stats2, invM);
    bn_apply2_kernel<<<(M / 2 + 255) / 256, 256, 0, stream>>>(h2, stats2, (float*)d_out, M / 2);
}

// Round 8
// 216.743 us; speedup vs baseline: 25.5091x; 1.1330x over previous
//
#include <hip/hip_runtime.h>

#define N_NODES 50000
#define BN_EPS 1e-5f
#define NBUCK 391
#define NCHUNK 1000
#define ENTCAP 5120

using short8 = __attribute__((ext_vector_type(8))) short;
using f32x4  = __attribute__((ext_vector_type(4))) float;

__device__ __forceinline__ float b2f(ushort h) { return __uint_as_float(((uint)h) << 16); }
__device__ __forceinline__ float blo(uint v) { return __uint_as_float(v << 16); }
__device__ __forceinline__ float bhi(uint v) { return __uint_as_float(v & 0xffff0000u); }
__device__ __forceinline__ ushort f2b(float f) {
    uint u = __float_as_uint(f);
    u += 0x7FFF + ((u >> 16) & 1);   // round-to-nearest-even
    return (ushort)(u >> 16);
}
__device__ __forceinline__ uint packb(float lo, float hi) {
    return ((uint)f2b(hi) << 16) | (uint)f2b(lo);
}
__device__ __forceinline__ int xcd_chunk(int bid) {
    return (bid & 7) * (NCHUNK / 8) + (bid >> 3);
}

// ================= setup mega-kernel: hist | convert_x | convert_w | zero =================
#define B_CX 6250   // M*32/256
#define B_CW 192    // 3*16384/256
#define B_Z  8      // 2048 floats of statsrep
__global__ __launch_bounds__(256) void setup_kernel(const int* __restrict__ dst, int nE, int chunk,
                                                    int* __restrict__ histT,
                                                    const float4* __restrict__ x4,
                                                    ushort4* __restrict__ xb,
                                                    const float* __restrict__ w11,
                                                    const float* __restrict__ w12,
                                                    const float* __restrict__ w21,
                                                    ushort* __restrict__ o11,
                                                    ushort* __restrict__ o12,
                                                    ushort* __restrict__ o21,
                                                    float* __restrict__ statsrep) {
    __shared__ int h[NBUCK];
    const int b = blockIdx.x;
    const int tid = threadIdx.x;
    if (b < NCHUNK) {
        for (int i = tid; i < NBUCK; i += 256) h[i] = 0;
        __syncthreads();
        const int c = xcd_chunk(b);
        const int lo = c * chunk, hi = min(lo + chunk, nE);
        for (int i = lo + tid; i < hi; i += 256) atomicAdd(&h[dst[i] >> 7], 1);
        __syncthreads();
        for (int k = tid; k < NBUCK; k += 256) histT[k * NCHUNK + c] = h[k];
    } else if (b < NCHUNK + B_CX) {
        int i = (b - NCHUNK) * 256 + tid;
        float4 v = x4[i];
        ushort4 o;
        o.x = f2b(v.x); o.y = f2b(v.y); o.z = f2b(v.z); o.w = f2b(v.w);
        xb[i] = o;
    } else if (b < NCHUNK + B_CX + B_CW) {
        int id = (b - NCHUNK - B_CX) * 256 + tid;     // 0..49151
        int m = id >> 14;
        int within = id & 16383;
        int k = within >> 7, n = within & 127;
        const float* W = (m == 0) ? w11 : (m == 1) ? w12 : w21;
        ushort* O = (m == 0) ? o11 : (m == 1) ? o12 : o21;
        O[n * 128 + k] = f2b(W[within]);
    } else {
        int i = (b - NCHUNK - B_CX - B_CW) * 256 + tid;
        if (i < 2048) statsrep[i] = 0.f;
    }
}

// ================= radix: per-bucket totals =================
__global__ __launch_bounds__(256) void tot_kernel(const int* __restrict__ histT,
                                                  int* __restrict__ tot) {
    __shared__ int s[256];
    int acc = 0;
    for (int i = threadIdx.x; i < NCHUNK; i += 256) acc += histT[blockIdx.x * NCHUNK + i];
    s[threadIdx.x] = acc;
    __syncthreads();
    for (int d = 128; d > 0; d >>= 1) {
        if (threadIdx.x < d) s[threadIdx.x] += s[threadIdx.x + d];
        __syncthreads();
    }
    if (threadIdx.x == 0) tot[blockIdx.x] = s[0];
}

// ================= radix: per-bucket base + per-chunk exclusive offsets =================
__global__ __launch_bounds__(1024) void base_scan_kernel(const int* __restrict__ tot,
                                                         const int* __restrict__ histT,
                                                         int* __restrict__ base_bc,
                                                         int* __restrict__ bucketbase,
                                                         int* __restrict__ rowptr, int nE) {
    __shared__ int s[1024];
    const int b = blockIdx.x;
    const int t = threadIdx.x;
    int acc = 0;
    for (int i = t; i < b; i += 1024) acc += tot[i];
    s[t] = acc;
    __syncthreads();
    for (int d = 512; d > 0; d >>= 1) {
        if (t < d) s[t] += s[t + d];
        __syncthreads();
    }
    const int bbase = s[0];
    __syncthreads();
    int v = (t < NCHUNK) ? histT[b * NCHUNK + t] : 0;
    s[t] = v;
    __syncthreads();
    for (int d = 1; d < 1024; d <<= 1) {
        int u = (t >= d) ? s[t - d] : 0;
        __syncthreads();
        s[t] += u;
        __syncthreads();
    }
    if (t < NCHUNK) base_bc[b * NCHUNK + t] = bbase + s[t] - v;  // exclusive
    if (t == 0) {
        bucketbase[b] = bbase;
        if (b == NBUCK - 1) bucketbase[NBUCK] = bbase + tot[b];
        if (b == 0) rowptr[N_NODES] = nE;
    }
}

// ================= radix pass 2: placement =================
__global__ __launch_bounds__(256) void place_kernel(const int* __restrict__ src,
                                                    const int* __restrict__ dst, int nE,
                                                    int chunk,
                                                    const int* __restrict__ base_bc,
                                                    uint* __restrict__ bdata) {
    __shared__ int off[NBUCK];
    const int c = xcd_chunk(blockIdx.x);
    for (int i = threadIdx.x; i < NBUCK; i += 256) off[i] = base_bc[i * NCHUNK + c];
    __syncthreads();
    const int lo = c * chunk, hi = min(lo + chunk, nE);
    for (int i = lo + threadIdx.x; i < hi; i += 256) {
        int s = src[i], d = dst[i];
        int pos = atomicAdd(&off[d >> 7], 1);
        bdata[pos] = ((uint)(d & 127) << 16) | (uint)s;
    }
}

// ================= per-bucket LDS counting sort -> rowptr + perm =================
__global__ __launch_bounds__(256) void csr_build_kernel(const int* __restrict__ bucketbase,
                                                        const uint* __restrict__ bdata,
                                                        int* __restrict__ rowptr,
                                                        ushort* __restrict__ perm, int M) {
    __shared__ uint ent[ENTCAP];
    __shared__ int hist[128];
    __shared__ int scn[128];
    __shared__ int cur[128];
    const int b = blockIdx.x;
    const int tid = threadIdx.x;
    const int bb = bucketbase[b];
    const int nb = min(bucketbase[b + 1] - bb, ENTCAP);
    if (tid < 128) hist[tid] = 0;
    for (int i = tid; i < nb; i += 256) ent[i] = bdata[bb + i];
    __syncthreads();
    for (int i = tid; i < nb; i += 256) atomicAdd(&hist[ent[i] >> 16], 1);
    __syncthreads();
    if (tid < 128) scn[tid] = hist[tid];
    __syncthreads();
    for (int d = 1; d < 128; d <<= 1) {
        int v = 0;
        if (tid < 128 && tid >= d) v = scn[tid - d];
        __syncthreads();
        if (tid < 128) scn[tid] += v;
        __syncthreads();
    }
    if (tid < 128) {
        int ex = scn[tid] - hist[tid];
        cur[tid] = ex;
        int node = b * 128 + tid;
        if (node < M) rowptr[node] = bb + ex;
    }
    __syncthreads();
    for (int i = tid; i < nb; i += 256) {
        uint e = ent[i];
        int lp = atomicAdd(&cur[e >> 16], 1);
        perm[bb + lp] = (ushort)(e & 0xffffu);
    }
}

// ================= gather (16 lanes/edge, 4-deep), optional fused BN finalize+apply ======
#define ACC4(v) { acc[0] += blo(v.x); acc[1] += bhi(v.x); \
                  acc[2] += blo(v.y); acc[3] += bhi(v.y); \
                  acc[4] += blo(v.z); acc[5] += bhi(v.z); \
                  acc[6] += blo(v.w); acc[7] += bhi(v.w); }

template<bool BN>
__global__ __launch_bounds__(256) void gather_kernel(const uint4* __restrict__ xb,
                                                     const int* __restrict__ rowptr,
                                                     const ushort* __restrict__ perm,
                                                     const float* __restrict__ statsrep,
                                                     const float* __restrict__ gma,
                                                     const float* __restrict__ bta,
                                                     float invM,
                                                     uint4* __restrict__ out, int M) {
    __shared__ float scs[128], shs[128];
    if (BN) {
        if (threadIdx.x < 128) {
            int c = threadIdx.x;
            float s = 0.f, q = 0.f;
            #pragma unroll
            for (int rep = 0; rep < 8; ++rep) {
                s += statsrep[rep * 256 + c];
                q += statsrep[rep * 256 + 128 + c];
            }
            float mean = s * invM;
            float var = q * invM - mean * mean;
            float sc = rsqrtf(var + BN_EPS) * gma[c];
            scs[c] = sc;
            shs[c] = bta[c] - mean * sc;
        }
        __syncthreads();
    }
    const int node = blockIdx.x * 4 + (threadIdx.x >> 6);
    if (node >= M) return;
    const int lane = threadIdx.x & 63;
    const int g4 = lane >> 4;       // edge slot 0..3
    const int r = lane & 15;        // 16B chunk (features r*8 .. r*8+7)
    float acc[8];
    if (g4 == 0) {
        uint4 v = xb[node * 16 + r];
        acc[0] = blo(v.x); acc[1] = bhi(v.x);
        acc[2] = blo(v.y); acc[3] = bhi(v.y);
        acc[4] = blo(v.z); acc[5] = bhi(v.z);
        acc[6] = blo(v.w); acc[7] = bhi(v.w);
    } else {
        #pragma unroll
        for (int k = 0; k < 8; ++k) acc[k] = 0.f;
    }
    const int beg = rowptr[node], end = rowptr[node + 1];
    int e = beg + g4;
    while (e + 12 < end) {
        int s0 = perm[e], s1 = perm[e + 4], s2 = perm[e + 8], s3 = perm[e + 12];
        uint4 v0 = xb[s0 * 16 + r];
        uint4 v1 = xb[s1 * 16 + r];
        uint4 v2 = xb[s2 * 16 + r];
        uint4 v3 = xb[s3 * 16 + r];
        ACC4(v0); ACC4(v1); ACC4(v2); ACC4(v3);
        e += 16;
    }
    while (e + 4 < end) {
        int s0 = perm[e], s1 = perm[e + 4];
        uint4 v0 = xb[s0 * 16 + r];
        uint4 v1 = xb[s1 * 16 + r];
        ACC4(v0); ACC4(v1);
        e += 8;
    }
    if (e < end) {
        uint4 v0 = xb[(int)perm[e] * 16 + r];
        ACC4(v0);
    }
    #pragma unroll
    for (int k = 0; k < 8; ++k) {
        acc[k] += __shfl_xor(acc[k], 16);
        acc[k] += __shfl_xor(acc[k], 32);
    }
    if (g4 == 0) {
        if (BN) {
            const int f0 = r * 8;
            const float deg1 = (float)(end - beg + 1);
            #pragma unroll
            for (int k = 0; k < 8; ++k)
                acc[k] = acc[k] * scs[f0 + k] + deg1 * shs[f0 + k];
        }
        uint4 o;
        o.x = packb(acc[0], acc[1]);
        o.y = packb(acc[2], acc[3]);
        o.z = packb(acc[4], acc[5]);
        o.w = packb(acc[6], acc[7]);
        out[node * 16 + r] = o;
    }
}

// ================= fused layer-1: relu(A@W11+b11)@W12+b12 -> relu -> C + stats ============
__global__ __launch_bounds__(256) void mmL1_fused_kernel(const ushort* __restrict__ A,
                                                         const ushort* __restrict__ Wt1,
                                                         const float* __restrict__ b1,
                                                         const ushort* __restrict__ Wt2,
                                                         const float* __restrict__ b2,
                                                         ushort* __restrict__ C,
                                                         float* __restrict__ statsrep, int M) {
    __shared__ float T[4][64][33];
    const int wid = threadIdx.x >> 6;
    const int lane = threadIdx.x & 63;
    const int row0 = blockIdx.x * 64;
    const int r = lane & 15;
    const int kg = lane >> 4;

    const int arow = min(row0 + wid * 16 + r, M - 1);
    const ushort* Arow = A + (size_t)arow * 128 + kg * 8;
    short8 a[4];
    #pragma unroll
    for (int kb = 0; kb < 4; ++kb)
        a[kb] = *(const short8*)(Arow + kb * 32);

    // GEMM1 -> LDS (pre-relu'd f32)
    #pragma unroll
    for (int c = 0; c < 8; ++c) {
        f32x4 acc = {0.f, 0.f, 0.f, 0.f};
        const ushort* Wcol = Wt1 + (size_t)(c * 16 + r) * 128 + kg * 8;
        #pragma unroll
        for (int kb = 0; kb < 4; ++kb) {
            short8 bb = *(const short8*)(Wcol + kb * 32);
            acc = __builtin_amdgcn_mfma_f32_16x16x32_bf16(a[kb], bb, acc, 0, 0, 0);
        }
        const float bias = b1[c * 16 + r];
        const int kb_w = c >> 1;
        const int inner = ((c & 1) << 4) + r;
        #pragma unroll
        for (int j = 0; j < 4; ++j)
            T[kb_w][wid * 16 + kg * 4 + j][inner] = fmaxf(acc[j] + bias, 0.f);
    }
    __syncthreads();

    // A2 fragments from LDS
    const int lrow = wid * 16 + r;
    short8 a2[4];
    #pragma unroll
    for (int kb = 0; kb < 4; ++kb) {
        #pragma unroll
        for (int i = 0; i < 8; ++i)
            a2[kb][i] = (short)f2b(T[kb][lrow][kg * 8 + i]);
    }

    // GEMM2 + epilogue (store + stats)
    float* sr = statsrep + (blockIdx.x & 7) * 256;
    #pragma unroll
    for (int c = 0; c < 8; ++c) {
        f32x4 acc = {0.f, 0.f, 0.f, 0.f};
        const ushort* Wcol = Wt2 + (size_t)(c * 16 + r) * 128 + kg * 8;
        #pragma unroll
        for (int kb = 0; kb < 4; ++kb) {
            short8 bb = *(const short8*)(Wcol + kb * 32);
            acc = __builtin_amdgcn_mfma_f32_16x16x32_bf16(a2[kb], bb, acc, 0, 0, 0);
        }
        const float bias = b2[c * 16 + r];
        float s = 0.f, q = 0.f;
        #pragma unroll
        for (int j = 0; j < 4; ++j) {
            int orow = row0 + wid * 16 + kg * 4 + j;
            float v = fmaxf(acc[j] + bias, 0.f);
            if (orow < M) C[(size_t)orow * 128 + c * 16 + r] = f2b(v);
            else v = 0.f;
            s += v; q += v * v;
        }
        s += __shfl_xor(s, 16); s += __shfl_xor(s, 32);
        q += __shfl_xor(q, 16); q += __shfl_xor(q, 32);
        if (kg == 0) {
            atomicAdd(&sr[c * 16 + r], s);
            atomicAdd(&sr[128 + c * 16 + r], q);
        }
    }
}

// ================= fused layer-2 tail: relu(A@W21+b21)@W22+b22 -> relu -> h2 + pblk ======
__global__ __launch_bounds__(256) void mm2_fused_kernel(const ushort* __restrict__ A,
                                                        const ushort* __restrict__ Wt,
                                                        const float* __restrict__ b1,
                                                        const float* __restrict__ W22,
                                                        const float* __restrict__ b22,
                                                        float* __restrict__ h2,
                                                        float4* __restrict__ pblk, int M) {
    __shared__ float bred[4][4];
    const int wid = threadIdx.x >> 6;
    const int lane = threadIdx.x & 63;
    const int row0 = blockIdx.x * 64 + wid * 16;
    const int r = lane & 15;
    const int kg = lane >> 4;

    const int arow = min(row0 + r, M - 1);
    const ushort* Arow = A + (size_t)arow * 128 + kg * 8;
    short8 a[4];
    #pragma unroll
    for (int kb = 0; kb < 4; ++kb)
        a[kb] = *(const short8*)(Arow + kb * 32);

    float w2a[8], w2b[8];
    #pragma unroll
    for (int c = 0; c < 8; ++c) {
        w2a[c] = W22[(c * 16 + r) * 2 + 0];
        w2b[c] = W22[(c * 16 + r) * 2 + 1];
    }

    float s0[4] = {0.f, 0.f, 0.f, 0.f};
    float s1[4] = {0.f, 0.f, 0.f, 0.f};
    #pragma unroll
    for (int c = 0; c < 8; ++c) {
        f32x4 acc = {0.f, 0.f, 0.f, 0.f};
        const ushort* Wcol = Wt + (size_t)(c * 16 + r) * 128 + kg * 8;
        #pragma unroll
        for (int kb = 0; kb < 4; ++kb) {
            short8 bb = *(const short8*)(Wcol + kb * 32);
            acc = __builtin_amdgcn_mfma_f32_16x16x32_bf16(a[kb], bb, acc, 0, 0, 0);
        }
        float bias = b1[c * 16 + r];
        #pragma unroll
        for (int j = 0; j < 4; ++j) {
            int orow = row0 + kg * 4 + j;
            float v = fmaxf(acc[j] + bias, 0.f);
            if (orow >= M) v = 0.f;
            s0[j] += v * w2a[c];
            s1[j] += v * w2b[c];
        }
    }
    #pragma unroll
    for (int j = 0; j < 4; ++j) {
        #pragma unroll
        for (int d = 1; d < 16; d <<= 1) {
            s0[j] += __shfl_xor(s0[j], d);
            s1[j] += __shfl_xor(s1[j], d);
        }
    }
    float bs[4] = {0.f, 0.f, 0.f, 0.f};
    if (r == 0) {
        const float bb0 = b22[0], bb1 = b22[1];
        #pragma unroll
        for (int j = 0; j < 4; ++j) {
            int orow = row0 + kg * 4 + j;
            if (orow < M) {
                float o0 = fmaxf(s0[j] + bb0, 0.f);
                float o1 = fmaxf(s1[j] + bb1, 0.f);
                h2[(size_t)orow * 2 + 0] = o0;
                h2[(size_t)orow * 2 + 1] = o1;
                bs[0] += o0; bs[1] += o1; bs[2] += o0 * o0; bs[3] += o1 * o1;
            }
        }
    }
    #pragma unroll
    for (int k = 0; k < 4; ++k) {
        bs[k] += __shfl_xor(bs[k], 16);
        bs[k] += __shfl_xor(bs[k], 32);
    }
    if (lane == 0) {
        #pragma unroll
        for (int k = 0; k < 4; ++k) bred[wid][k] = bs[k];
    }
    __syncthreads();
    if (threadIdx.x == 0)
        pblk[blockIdx.x] = make_float4(bred[0][0] + bred[1][0] + bred[2][0] + bred[3][0],
                                       bred[0][1] + bred[1][1] + bred[2][1] + bred[3][1],
                                       bred[0][2] + bred[1][2] + bred[2][2] + bred[3][2],
                                       bred[0][3] + bred[1][3] + bred[2][3] + bred[3][3]);
}

// ================= final: reduce pblk -> BN2 scale/shift -> apply, f32 out =================
__global__ __launch_bounds__(256) void bn_apply2_kernel(const float* __restrict__ h,
                                                        const float4* __restrict__ pblk, int nblk,
                                                        const float* __restrict__ gma,
                                                        const float* __restrict__ bta,
                                                        float* __restrict__ y, int n4, float invM) {
    __shared__ float4 red[256];
    const int tid = threadIdx.x;
    float4 s = make_float4(0.f, 0.f, 0.f, 0.f);
    for (int b = tid; b < nblk; b += 256) {
        float4 t = pblk[b];
        s.x += t.x; s.y += t.y; s.z += t.z; s.w += t.w;
    }
    red[tid] = s;
    __syncthreads();
    for (int d = 128; d > 0; d >>= 1) {
        if (tid < d) {
            red[tid].x += red[tid + d].x;
            red[tid].y += red[tid + d].y;
            red[tid].z += red[tid + d].z;
            red[tid].w += red[tid + d].w;
        }
        __syncthreads();
    }
    const float4 tot = red[0];
    const float m0 = tot.x * invM, m1 = tot.y * invM;
    const float v0 = tot.z * invM - m0 * m0, v1 = tot.w * invM - m1 * m1;
    const float sc0 = rsqrtf(v0 + BN_EPS) * gma[0], sc1 = rsqrtf(v1 + BN_EPS) * gma[1];
    const float sh0 = bta[0] - m0 * sc0, sh1 = bta[1] - m1 * sc1;
    int gid = blockIdx.x * 256 + tid;
    if (gid >= n4) return;
    float4 v = ((const float4*)h)[gid];
    float4 o;
    o.x = v.x * sc0 + sh0;
    o.y = v.y * sc1 + sh1;
    o.z = v.z * sc0 + sh0;
    o.w = v.w * sc1 + sh1;
    ((float4*)y)[gid] = o;
}

extern "C" void kernel_launch(void* const* d_in, const int* in_sizes, int n_in,
                              void* d_out, int out_size, void* d_ws, size_t ws_size,
                              hipStream_t stream) {
    const float* x   = (const float*)d_in[0];
    const int*   ei  = (const int*)d_in[1];
    const float* w11 = (const float*)d_in[2];
    const float* b11 = (const float*)d_in[3];
    const float* w12 = (const float*)d_in[4];
    const float* b12 = (const float*)d_in[5];
    const float* g1  = (const float*)d_in[6];
    const float* be1 = (const float*)d_in[7];
    const float* w21 = (const float*)d_in[8];
    const float* b21 = (const float*)d_in[9];
    const float* w22 = (const float*)d_in[10];
    const float* b22 = (const float*)d_in[11];
    const float* g2  = (const float*)d_in[12];
    const float* be2 = (const float*)d_in[13];

    const int M  = N_NODES;
    const int nE = in_sizes[1] / 2;
    const int* src = ei;
    const int* dst = ei + nE;
    const int chunk = (nE + NCHUNK - 1) / NCHUNK;
    const int nblk = (M + 63) / 64;

    const size_t RB = (size_t)50048 * 128 * 2;      // padded bf16 feature buffer bytes
    char* p = (char*)d_ws;
    ushort* xb   = (ushort*)p;  p += RB;
    ushort* gbuf = (ushort*)p;  p += RB;
    ushort* hbuf = (ushort*)p;  p += RB;
    float*  h2   = (float*)p;   p += 400128;        // 50000*2 f32
    ushort* wt11 = (ushort*)p;  p += 32768;
    ushort* wt12 = (ushort*)p;  p += 32768;
    ushort* wt21 = (ushort*)p;  p += 32768;
    float* statsrep = (float*)p; p += 2048 * 4;     // 8 x (sum[128], sumsq[128])
    float4* pblk = (float4*)p;  p += (size_t)nblk * 16 + 64;
    int*  histT  = (int*)p;     p += (size_t)NBUCK * NCHUNK * 4;
    int*  base_bc= (int*)p;     p += (size_t)NBUCK * NCHUNK * 4;
    int*  tot    = (int*)p;     p += 512 * 4;
    int*  bktbase= (int*)p;     p += 512 * 4;
    int*  rowptr = (int*)p;     p += (size_t)(M + 8) * 4;
    ushort* perm = (ushort*)p;  p += (size_t)nE * 2 + 64;
    uint*  bdata = (uint*)p;

    const float invM = 1.0f / (float)M;

    // ---- setup: hist + convert_x + convert_w + zero (one dispatch) ----
    setup_kernel<<<NCHUNK + B_CX + B_CW + B_Z, 256, 0, stream>>>(
        dst, nE, chunk, histT, (const float4*)x, (ushort4*)xb,
        w11, w12, w21, wt11, wt12, wt21, statsrep);
    // ---- CSR build ----
    tot_kernel<<<NBUCK, 256, 0, stream>>>(histT, tot);
    base_scan_kernel<<<NBUCK, 1024, 0, stream>>>(tot, histT, base_bc, bktbase, rowptr, nE);
    place_kernel<<<NCHUNK, 256, 0, stream>>>(src, dst, nE, chunk, base_bc, bdata);
    csr_build_kernel<<<NBUCK, 256, 0, stream>>>(bktbase, bdata, rowptr, perm, M);

    // ---- layer 1 ----
    gather_kernel<false><<<(M + 3) / 4, 256, 0, stream>>>((const uint4*)xb, rowptr, perm,
                                                          nullptr, nullptr, nullptr, 0.f,
                                                          (uint4*)gbuf, M);
    mmL1_fused_kernel<<<nblk, 256, 0, stream>>>(gbuf, wt11, b11, wt12, b12, hbuf, statsrep, M);

    // ---- layer 2 (BN1 finalize+fold fused into gather) ----
    gather_kernel<true><<<(M + 3) / 4, 256, 0, stream>>>((const uint4*)hbuf, rowptr, perm,
                                                         statsrep, g1, be1, invM,
                                                         (uint4*)gbuf, M);
    mm2_fused_kernel<<<nblk, 256, 0, stream>>>(gbuf, wt21, b21, w22, b22, h2, pblk, M);
    bn_apply2_kernel<<<(M / 2 + 255) / 256, 256, 0, stream>>>(h2, pblk, nblk, g2, be2,
                                                              (float*)d_out, M / 2, invM);
}